// Round 1
// baseline (644.366 us; speedup 1.0000x reference)
//
#include <hip/hip_runtime.h>
#include <stdint.h>

// Problem constants (B=2,S=1024,D=1024,F=4096,E=8)
#define T_TOK 2048
#define D_DIM 1024
#define F_DIM 4096
#define E_NUM 8
#define RPMAX 3072   // max padded rows: sum of per-expert ceil(cnt,128)
#define BK 64

typedef __attribute__((ext_vector_type(8))) short bfx8;   // 8 bf16 (4 VGPR)
typedef __attribute__((ext_vector_type(4))) short bfx4;   // 4 bf16 (8B)
typedef __attribute__((ext_vector_type(4))) float fx4;    // MFMA accum

__device__ __forceinline__ unsigned short f2bf(float f) {
  union { float f; uint32_t u; } v; v.f = f;
  uint32_t u = v.u;
  u += 0x7FFFu + ((u >> 16) & 1u);   // round-to-nearest-even
  return (unsigned short)(u >> 16);
}

// ---------------- router: logits, softmax, argmax, counts ----------------
__global__ __launch_bounds__(64) void router_kernel(
    const float* __restrict__ x, const float* __restrict__ sw,
    const float* __restrict__ sb, float* __restrict__ pmax_out,
    int* __restrict__ routes, int* __restrict__ counts,
    float* __restrict__ psums) {
  const int t = blockIdx.x;
  const int lane = threadIdx.x;
  float acc[8];
#pragma unroll
  for (int e = 0; e < 8; ++e) acc[e] = 0.f;
  const float* xr = x + (size_t)t * D_DIM;
#pragma unroll 4
  for (int i = 0; i < D_DIM / 64; ++i) {
    int d = i * 64 + lane;
    float xv = xr[d];
    const float4* swp = (const float4*)(sw + (size_t)d * 8);
    float4 w0 = swp[0], w1 = swp[1];
    acc[0] += xv * w0.x; acc[1] += xv * w0.y; acc[2] += xv * w0.z; acc[3] += xv * w0.w;
    acc[4] += xv * w1.x; acc[5] += xv * w1.y; acc[6] += xv * w1.z; acc[7] += xv * w1.w;
  }
#pragma unroll
  for (int e = 0; e < 8; ++e) {
    float v = acc[e];
    for (int o = 32; o > 0; o >>= 1) v += __shfl_down(v, o, 64);
    acc[e] = v;
  }
  if (lane == 0) {
#pragma unroll
    for (int e = 0; e < 8; ++e) acc[e] += sb[e];
    int am = 0; float mx = acc[0];
#pragma unroll
    for (int e = 1; e < 8; ++e) if (acc[e] > mx) { mx = acc[e]; am = e; }  // first-max wins (matches np argmax)
    float p[8]; float s = 0.f;
#pragma unroll
    for (int e = 0; e < 8; ++e) { p[e] = expf(acc[e] - mx); s += p[e]; }
    float inv = 1.0f / s;
    pmax_out[t] = inv;   // softmax at argmax = exp(0)/s
    routes[t] = am;
    atomicAdd(&counts[am], 1);
#pragma unroll
    for (int e = 0; e < 8; ++e) atomicAdd(&psums[e], p[e] * inv);
  }
}

// ---------------- plan: 128-aligned segment offsets + small outputs ----------------
__global__ __launch_bounds__(64) void plan_kernel(
    const int* __restrict__ counts, const float* __restrict__ psums,
    int* __restrict__ off, float* __restrict__ out_counts,
    float* __restrict__ out_psums, float* __restrict__ out_zero) {
  int t = threadIdx.x;
  if (t == 0) {
    int o = 0;
    for (int e = 0; e < 8; ++e) { off[e] = o; o += ((counts[e] + 127) >> 7) << 7; }
    off[8] = o;
    *out_zero = 0.0f;
  }
  if (t < 8) {
    out_counts[t] = (float)counts[t];
    out_psums[t] = psums[t];
  }
}

// ---------------- scatter: token -> gathered slot ----------------
__global__ __launch_bounds__(256) void scatter_kernel(
    const int* __restrict__ routes, const int* __restrict__ off,
    int* __restrict__ cursor, int* __restrict__ perm) {
  int t = blockIdx.x * 256 + threadIdx.x;
  if (t >= T_TOK) return;
  int e = routes[t];
  int pos = atomicAdd(&cursor[e], 1);
  perm[off[e] + pos] = t;
}

// ---------------- grouped GEMM (both FFN layers) ----------------
// FIRST: H = relu(gather(X) @ W1[e] + b1[e]) stored bf16
// else : Out[tok] = (H @ W2[e] + b2[e]) * pmax[tok] scattered fp32
template <int BM, int BN, int WM, int WN, int K_, int N_, bool FIRST>
__global__ __launch_bounds__(256) void gemm_kernel(
    const float* __restrict__ X, const unsigned short* __restrict__ Hin,
    const float* __restrict__ W, const float* __restrict__ Bias,
    const int* __restrict__ off, const int* __restrict__ perm,
    const float* __restrict__ pmax, unsigned short* __restrict__ Hout,
    float* __restrict__ Out) {
  constexpr int FM = WM / 16, FN = WN / 16;
  constexpr int WAVES_N = BN / WN;
  __shared__ unsigned short As[BM * BK];
  __shared__ unsigned short Bs[BN * BK];
  const int tid = threadIdx.x;
  const int rowbase = blockIdx.y * BM;
  const int total = off[8];
  if (rowbase >= total) return;
  int e = 0;
#pragma unroll
  for (int i = 1; i <= 7; ++i) if (rowbase >= off[i]) e = i;
  const int n0 = blockIdx.x * BN;
  const float* We = W + (size_t)e * K_ * N_;
  const int wave = tid >> 6, lane = tid & 63;
  const int wm = wave / WAVES_N, wn = wave % WAVES_N;
  char* Ab = (char*)As;
  char* Bb = (char*)Bs;

  fx4 acc[FM][FN];
#pragma unroll
  for (int a = 0; a < FM; ++a)
#pragma unroll
    for (int b = 0; b < FN; ++b) acc[a][b] = (fx4){0.f, 0.f, 0.f, 0.f};

  for (int k0 = 0; k0 < K_; k0 += BK) {
    // ---- stage A ----
    if (FIRST) {
#pragma unroll
      for (int it = 0; it < BM / 16; ++it) {   // BM*16 float4-chunks / 256 thr
        int id = it * 256 + tid;
        int row = id >> 4, kq = id & 15;
        int tok = perm[rowbase + row];
        float4 v = make_float4(0.f, 0.f, 0.f, 0.f);
        if (tok >= 0) v = *(const float4*)(X + (size_t)tok * D_DIM + k0 + kq * 4);
        bfx4 h;
        h.x = (short)f2bf(v.x); h.y = (short)f2bf(v.y);
        h.z = (short)f2bf(v.z); h.w = (short)f2bf(v.w);
        *(bfx4*)(Ab + row * 128 + ((kq * 8) ^ ((row & 7) << 4))) = h;
      }
    } else {
#pragma unroll
      for (int it = 0; it < BM / 32; ++it) {   // BM*8 16B-chunks / 256 thr
        int id = it * 256 + tid;
        int row = id >> 3, kq = id & 7;
        bfx8 v = *(const bfx8*)(Hin + (size_t)(rowbase + row) * F_DIM + k0 + kq * 8);
        *(bfx8*)(Ab + row * 128 + ((kq * 16) ^ ((row & 7) << 4))) = v;
      }
    }
    // ---- stage B (k-strided coalesced dword loads -> [n][k] LDS) ----
#pragma unroll
    for (int it = 0; it < BN / 32; ++it) {     // BN*(BK/8) chunks / 256 thr
      int c = it * 256 + tid;
      int n = c & (BN - 1);
      int kc = c / BN;
      const float* src = We + (size_t)(k0 + kc * 8) * N_ + n0 + n;
      bfx8 v;
#pragma unroll
      for (int j = 0; j < 8; ++j) v[j] = (short)f2bf(src[(size_t)j * N_]);
      *(bfx8*)(Bb + n * 128 + ((kc * 16) ^ ((n & 7) << 4))) = v;
    }
    __syncthreads();
    // ---- MFMA ----
#pragma unroll
    for (int kk = 0; kk < 2; ++kk) {
      const int kb = kk * 64 + (lane >> 4) * 16;
      bfx8 af[FM], bfr[FN];
#pragma unroll
      for (int fm = 0; fm < FM; ++fm) {
        int r = wm * WM + fm * 16 + (lane & 15);
        af[fm] = *(const bfx8*)(Ab + r * 128 + (kb ^ ((r & 7) << 4)));
      }
#pragma unroll
      for (int fn = 0; fn < FN; ++fn) {
        int nn = wn * WN + fn * 16 + (lane & 15);
        bfr[fn] = *(const bfx8*)(Bb + nn * 128 + (kb ^ ((nn & 7) << 4)));
      }
#pragma unroll
      for (int fm = 0; fm < FM; ++fm)
#pragma unroll
        for (int fn = 0; fn < FN; ++fn)
          acc[fm][fn] = __builtin_amdgcn_mfma_f32_16x16x32_bf16(
              af[fm], bfr[fn], acc[fm][fn], 0, 0, 0);
    }
    __syncthreads();
  }

  // ---- epilogue ----
  const int colbase = n0 + wn * WN;
  if (FIRST) {
#pragma unroll
    for (int fn = 0; fn < FN; ++fn) {
      int colg = colbase + fn * 16 + (lane & 15);
      float bv = Bias[(size_t)e * N_ + colg];
#pragma unroll
      for (int fm = 0; fm < FM; ++fm) {
        int r = rowbase + wm * WM + fm * 16 + ((lane >> 4) << 2);
#pragma unroll
        for (int j = 0; j < 4; ++j) {
          float v = fmaxf(acc[fm][fn][j] + bv, 0.f);
          Hout[(size_t)(r + j) * F_DIM + colg] = f2bf(v);
        }
      }
    }
  } else {
#pragma unroll
    for (int fm = 0; fm < FM; ++fm) {
      int rb2 = rowbase + wm * WM + fm * 16 + ((lane >> 4) << 2);
#pragma unroll
      for (int j = 0; j < 4; ++j) {
        int tok = perm[rb2 + j];
        if (tok < 0) continue;
        float pm = pmax[tok];
#pragma unroll
        for (int fn = 0; fn < FN; ++fn) {
          int colg = colbase + fn * 16 + (lane & 15);
          float v = (acc[fm][fn][j] + Bias[(size_t)e * N_ + colg]) * pm;
          Out[(size_t)tok * D_DIM + colg] = v;
        }
      }
    }
  }
}

extern "C" void kernel_launch(void* const* d_in, const int* in_sizes, int n_in,
                              void* d_out, int out_size, void* d_ws, size_t ws_size,
                              hipStream_t stream) {
  const float* x  = (const float*)d_in[0];
  const float* sw = (const float*)d_in[1];
  const float* sb = (const float*)d_in[2];
  const float* w1 = (const float*)d_in[3];
  const float* b1 = (const float*)d_in[4];
  const float* w2 = (const float*)d_in[5];
  const float* b2 = (const float*)d_in[6];
  float* out = (float*)d_out;

  char* ws = (char*)d_ws;
  int*   off    = (int*)(ws + 0);        // 9 ints
  int*   counts = (int*)(ws + 256);      // 8 ints
  int*   cursor = (int*)(ws + 512);      // 8 ints
  float* psums  = (float*)(ws + 768);    // 8 floats
  int*   routes = (int*)(ws + 1024);     // 2048 ints
  int*   perm   = (int*)(ws + 16384);    // RPMAX ints
  unsigned short* H = (unsigned short*)(ws + 32768);  // RPMAX x 4096 bf16 = 25.2 MB

  // d_out layout: final(2097152) | counts(8) | psums(8) | 0(1) | pmax(2048)
  float* out_final  = out;
  float* out_counts = out + 2097152;
  float* out_psums  = out + 2097160;
  float* out_zero   = out + 2097168;
  float* out_pmax   = out + 2097169;

  hipMemsetAsync(ws + 256, 0, 544, stream);          // counts, cursor, psums
  hipMemsetAsync(ws + 16384, 0xFF, RPMAX * 4, stream);  // perm = -1

  router_kernel<<<T_TOK, 64, 0, stream>>>(x, sw, sb, out_pmax, routes, counts, psums);
  plan_kernel<<<1, 64, 0, stream>>>(counts, psums, off, out_counts, out_psums, out_zero);
  scatter_kernel<<<(T_TOK + 255) / 256, 256, 0, stream>>>(routes, off, cursor, perm);

  // GEMM1: [RPMAX,1024] x [1024,4096] -> H (relu, bf16)
  gemm_kernel<128, 128, 64, 64, 1024, 4096, true>
      <<<dim3(F_DIM / 128, RPMAX / 128), 256, 0, stream>>>(
          x, nullptr, w1, b1, off, perm, nullptr, H, nullptr);
  // GEMM2: [RPMAX,4096] x [4096,1024] -> out (bias, *pmax, scatter fp32)
  gemm_kernel<64, 128, 32, 64, 4096, 1024, false>
      <<<dim3(D_DIM / 128, RPMAX / 64), 256, 0, stream>>>(
          nullptr, H, w2, b2, off, perm, out_pmax, nullptr, out_final);
}

// Round 2
// 437.894 us; speedup vs baseline: 1.4715x; 1.4715x over previous
//
#include <hip/hip_runtime.h>
#include <stdint.h>

// Problem constants (B=2,S=1024,D=1024,F=4096,E=8)
#define T_TOK 2048
#define D_DIM 1024
#define F_DIM 4096
#define E_NUM 8
#define RPMAX 3072   // max padded rows: sum of per-expert ceil(cnt,128) <= 2048+8*127
#define BK 64

typedef __attribute__((ext_vector_type(8))) short bfx8;   // 8 bf16 (4 VGPR)
typedef __attribute__((ext_vector_type(4))) short bfx4;   // 4 bf16 (8B)
typedef __attribute__((ext_vector_type(4))) float fx4;    // MFMA accum

__device__ __forceinline__ unsigned short f2bf(float f) {
  union { float f; uint32_t u; } v; v.f = f;
  uint32_t u = v.u;
  u += 0x7FFFu + ((u >> 16) & 1u);   // round-to-nearest-even
  return (unsigned short)(u >> 16);
}

__device__ __forceinline__ void load_lds16(const unsigned short* g, unsigned short* l) {
  __builtin_amdgcn_global_load_lds(
      (const __attribute__((address_space(1))) void*)g,
      (__attribute__((address_space(3))) void*)l, 16, 0, 0);
}

// ---------------- router: logits, softmax, argmax, counts, + x->bf16 ----------------
__global__ __launch_bounds__(64) void router_kernel(
    const float* __restrict__ x, const float* __restrict__ sw,
    const float* __restrict__ sb, float* __restrict__ pmax_out,
    int* __restrict__ routes, int* __restrict__ counts,
    float* __restrict__ psums, unsigned short* __restrict__ xbf) {
  const int t = blockIdx.x;
  const int lane = threadIdx.x;
  float acc[8];
#pragma unroll
  for (int e = 0; e < 8; ++e) acc[e] = 0.f;
  const float* xr = x + (size_t)t * D_DIM;
#pragma unroll 4
  for (int i = 0; i < D_DIM / 64; ++i) {
    int d = i * 64 + lane;
    float xv = xr[d];
    if (xbf) xbf[(size_t)t * D_DIM + d] = f2bf(xv);
    const float4* swp = (const float4*)(sw + (size_t)d * 8);
    float4 w0 = swp[0], w1 = swp[1];
    acc[0] += xv * w0.x; acc[1] += xv * w0.y; acc[2] += xv * w0.z; acc[3] += xv * w0.w;
    acc[4] += xv * w1.x; acc[5] += xv * w1.y; acc[6] += xv * w1.z; acc[7] += xv * w1.w;
  }
#pragma unroll
  for (int e = 0; e < 8; ++e) {
    float v = acc[e];
    for (int o = 32; o > 0; o >>= 1) v += __shfl_down(v, o, 64);
    acc[e] = v;
  }
  if (lane == 0) {
#pragma unroll
    for (int e = 0; e < 8; ++e) acc[e] += sb[e];
    int am = 0; float mx = acc[0];
#pragma unroll
    for (int e = 1; e < 8; ++e) if (acc[e] > mx) { mx = acc[e]; am = e; }  // first-max wins
    float p[8]; float s = 0.f;
#pragma unroll
    for (int e = 0; e < 8; ++e) { p[e] = expf(acc[e] - mx); s += p[e]; }
    float inv = 1.0f / s;
    pmax_out[t] = inv;   // softmax at argmax = exp(0)/s
    routes[t] = am;
    atomicAdd(&counts[am], 1);
#pragma unroll
    for (int e = 0; e < 8; ++e) atomicAdd(&psums[e], p[e] * inv);
  }
}

// ---------------- plan ----------------
__global__ __launch_bounds__(64) void plan_kernel(
    const int* __restrict__ counts, const float* __restrict__ psums,
    int* __restrict__ off, float* __restrict__ out_counts,
    float* __restrict__ out_psums, float* __restrict__ out_zero) {
  int t = threadIdx.x;
  if (t == 0) {
    int o = 0;
    for (int e = 0; e < 8; ++e) { off[e] = o; o += ((counts[e] + 127) >> 7) << 7; }
    off[8] = o;
    *out_zero = 0.0f;
  }
  if (t < 8) {
    out_counts[t] = (float)counts[t];
    out_psums[t] = psums[t];
  }
}

// ---------------- scatter: token -> gathered slot ----------------
__global__ __launch_bounds__(256) void scatter_kernel(
    const int* __restrict__ routes, const int* __restrict__ off,
    int* __restrict__ cursor, int* __restrict__ perm_out,
    int* __restrict__ perm_src) {
  int t = blockIdx.x * 256 + threadIdx.x;
  if (t >= T_TOK) return;
  int e = routes[t];
  int pos = atomicAdd(&cursor[e], 1);
  perm_out[off[e] + pos] = t;
  perm_src[off[e] + pos] = t;
}

// ---------------- convert+transpose: W fp32 [E][K][N] -> bf16 [E][N][K] ----------------
template <int K_, int N_>
__global__ __launch_bounds__(256) void conv_kernel(
    const float* __restrict__ W, unsigned short* __restrict__ WT) {
  __shared__ unsigned short tile[64][34];   // [k][n], pad to 34 u16 (68B rows)
  const int t = threadIdx.x;
  const int nbase = blockIdx.x * 32;
  const int kbase = blockIdx.y * 64;
  const int e = blockIdx.z;
  const float* We = W + (size_t)e * K_ * N_;
  unsigned short* WTe = WT + (size_t)e * N_ * K_;
  // phase 1: read 64k x 32n fp32 coalesced, convert, store LDS [k][n]
  {
    int kl = t >> 2;               // 0..63
    int nc = (t & 3) * 8;          // 0..24 step 8
    const float4* src = (const float4*)(We + (size_t)(kbase + kl) * N_ + nbase + nc);
    float4 a = src[0], b = src[1];
    unsigned short u[8] = {f2bf(a.x), f2bf(a.y), f2bf(a.z), f2bf(a.w),
                           f2bf(b.x), f2bf(b.y), f2bf(b.z), f2bf(b.w)};
#pragma unroll
    for (int p = 0; p < 4; ++p) {
      uint32_t pk = (uint32_t)u[2 * p] | ((uint32_t)u[2 * p + 1] << 16);
      *(uint32_t*)&tile[kl][nc + 2 * p] = pk;
    }
  }
  __syncthreads();
  // phase 2: write 32n x 64k bf16 coalesced along k
  {
    int nl = t >> 3;               // 0..31
    int kc = (t & 7) * 8;          // 0..56 step 8
    bfx8 v;
#pragma unroll
    for (int i = 0; i < 8; ++i) v[i] = (short)tile[kc + i][nl];
    *(bfx8*)(WTe + (size_t)(nbase + nl) * K_ + kbase + kc) = v;
  }
}

// ---------------- fast grouped GEMM (bf16 x bf16-transposed weights) ----------------
// FIRST: H = relu(gather(Xbf) @ W1T[e]^T + b1[e]) stored bf16 [RP][F]
// else : Out[tok] = (H @ W2T[e]^T + b2[e]) * pmax[tok] scattered fp32 [T][D]
template <int K_, int N_, bool FIRST>
__global__ __launch_bounds__(256) void gemm_fast(
    const unsigned short* __restrict__ A,    // FIRST: xbf [T][K_]; else H [RP][K_]
    const unsigned short* __restrict__ WT,   // [E][N_][K_] bf16
    const float* __restrict__ Bias,          // [E][N_]
    const int* __restrict__ off,
    const int* __restrict__ perm_src, const int* __restrict__ perm_out,
    const float* __restrict__ pmax,
    unsigned short* __restrict__ Hout, float* __restrict__ Out) {
  __shared__ __align__(16) unsigned short As[128 * 64];
  __shared__ __align__(16) unsigned short Bs[128 * 64];
  const int tid = threadIdx.x;
  const int rowbase = blockIdx.y * 128;
  if (rowbase >= off[8]) return;
  int e = 0;
#pragma unroll
  for (int i = 1; i <= 7; ++i) if (rowbase >= off[i]) e = i;
  const int n0 = blockIdx.x * 128;
  const int wave = tid >> 6, lane = tid & 63;
  const int wm = wave >> 1, wn = wave & 1;

  // per-lane pre-swizzled global source pointers (m173 pattern): LDS stays linear,
  // source chunk index is XOR'd so swizzled ds_reads retrieve logical data.
  const unsigned short* aSrc[4];
  const unsigned short* bSrc[4];
#pragma unroll
  for (int c = 0; c < 4; ++c) {
    int ca = (wave * 4 + c) * 64 + lane;      // 16B-chunk id, 0..1023
    int row = ca >> 3, slot = ca & 7;
    int sc = slot ^ (row & 7);
    size_t arow = FIRST ? (size_t)perm_src[rowbase + row] : (size_t)(rowbase + row);
    aSrc[c] = A + arow * K_ + sc * 8;
    bSrc[c] = WT + ((size_t)e * N_ + (n0 + row)) * (size_t)K_ + sc * 8;
  }
  unsigned short* aDst = As + wave * 2048;    // 4 chunks x 512 u16 per wave
  unsigned short* bDst = Bs + wave * 2048;

  fx4 acc[4][4];
#pragma unroll
  for (int a = 0; a < 4; ++a)
#pragma unroll
    for (int b = 0; b < 4; ++b) acc[a][b] = (fx4){0.f, 0.f, 0.f, 0.f};

  for (int k0 = 0; k0 < K_; k0 += BK) {
#pragma unroll
    for (int c = 0; c < 4; ++c) {
      load_lds16(aSrc[c] + k0, aDst + c * 512);
      load_lds16(bSrc[c] + k0, bDst + c * 512);
    }
    __syncthreads();
#pragma unroll
    for (int kk = 0; kk < 2; ++kk) {
      bfx8 af[4], bf[4];
#pragma unroll
      for (int fm = 0; fm < 4; ++fm) {
        int r = wm * 64 + fm * 16 + (lane & 15);
        int chunk = (kk * 4 + (lane >> 4)) ^ (r & 7);
        af[fm] = *(const bfx8*)(As + r * 64 + chunk * 8);
      }
#pragma unroll
      for (int fn = 0; fn < 4; ++fn) {
        int nn = wn * 64 + fn * 16 + (lane & 15);
        int chunk = (kk * 4 + (lane >> 4)) ^ (nn & 7);
        bf[fn] = *(const bfx8*)(Bs + nn * 64 + chunk * 8);
      }
#pragma unroll
      for (int fm = 0; fm < 4; ++fm)
#pragma unroll
        for (int fn = 0; fn < 4; ++fn)
          acc[fm][fn] = __builtin_amdgcn_mfma_f32_16x16x32_bf16(
              af[fm], bf[fn], acc[fm][fn], 0, 0, 0);
    }
    __syncthreads();
  }

  const int colbase = n0 + wn * 64;
  if (FIRST) {
#pragma unroll
    for (int fn = 0; fn < 4; ++fn) {
      int colg = colbase + fn * 16 + (lane & 15);
      float bv = Bias[(size_t)e * N_ + colg];
#pragma unroll
      for (int fm = 0; fm < 4; ++fm) {
        int rg = rowbase + wm * 64 + fm * 16 + ((lane >> 4) << 2);
#pragma unroll
        for (int j = 0; j < 4; ++j) {
          float v = fmaxf(acc[fm][fn][j] + bv, 0.f);
          Hout[(size_t)(rg + j) * N_ + colg] = f2bf(v);
        }
      }
    }
  } else {
#pragma unroll
    for (int fm = 0; fm < 4; ++fm) {
      int rg = rowbase + wm * 64 + fm * 16 + ((lane >> 4) << 2);
#pragma unroll
      for (int j = 0; j < 4; ++j) {
        int tok = perm_out[rg + j];
        if (tok < 0) continue;
        float pm = pmax[tok];
#pragma unroll
        for (int fn = 0; fn < 4; ++fn) {
          int colg = colbase + fn * 16 + (lane & 15);
          Out[(size_t)tok * N_ + colg] = (acc[fm][fn][j] + Bias[(size_t)e * N_ + colg]) * pm;
        }
      }
    }
  }
}

// ---------------- fallback grouped GEMM (round-1, fp32 weights in-loop) ----------------
template <int BM, int BN, int WM, int WN, int K_, int N_, bool FIRST>
__global__ __launch_bounds__(256) void gemm_kernel(
    const float* __restrict__ X, const unsigned short* __restrict__ Hin,
    const float* __restrict__ W, const float* __restrict__ Bias,
    const int* __restrict__ off, const int* __restrict__ perm,
    const float* __restrict__ pmax, unsigned short* __restrict__ Hout,
    float* __restrict__ Out) {
  constexpr int FM = WM / 16, FN = WN / 16;
  constexpr int WAVES_N = BN / WN;
  __shared__ unsigned short As[BM * BK];
  __shared__ unsigned short Bs[BN * BK];
  const int tid = threadIdx.x;
  const int rowbase = blockIdx.y * BM;
  if (rowbase >= off[8]) return;
  int e = 0;
#pragma unroll
  for (int i = 1; i <= 7; ++i) if (rowbase >= off[i]) e = i;
  const int n0 = blockIdx.x * BN;
  const float* We = W + (size_t)e * K_ * N_;
  const int wave = tid >> 6, lane = tid & 63;
  const int wm = wave / WAVES_N, wn = wave % WAVES_N;
  char* Ab = (char*)As;
  char* Bb = (char*)Bs;
  fx4 acc[FM][FN];
#pragma unroll
  for (int a = 0; a < FM; ++a)
#pragma unroll
    for (int b = 0; b < FN; ++b) acc[a][b] = (fx4){0.f, 0.f, 0.f, 0.f};
  for (int k0 = 0; k0 < K_; k0 += BK) {
    if (FIRST) {
#pragma unroll
      for (int it = 0; it < BM / 16; ++it) {
        int id = it * 256 + tid;
        int row = id >> 4, kq = id & 15;
        int tok = perm[rowbase + row];
        float4 v = make_float4(0.f, 0.f, 0.f, 0.f);
        if (tok >= 0) v = *(const float4*)(X + (size_t)tok * D_DIM + k0 + kq * 4);
        bfx4 h;
        h.x = (short)f2bf(v.x); h.y = (short)f2bf(v.y);
        h.z = (short)f2bf(v.z); h.w = (short)f2bf(v.w);
        *(bfx4*)(Ab + row * 128 + ((kq * 8) ^ ((row & 7) << 4))) = h;
      }
    } else {
#pragma unroll
      for (int it = 0; it < BM / 32; ++it) {
        int id = it * 256 + tid;
        int row = id >> 3, kq = id & 7;
        bfx8 v = *(const bfx8*)(Hin + (size_t)(rowbase + row) * F_DIM + k0 + kq * 8);
        *(bfx8*)(Ab + row * 128 + ((kq * 16) ^ ((row & 7) << 4))) = v;
      }
    }
#pragma unroll
    for (int it = 0; it < BN / 32; ++it) {
      int c = it * 256 + tid;
      int n = c & (BN - 1);
      int kc = c / BN;
      const float* src = We + (size_t)(k0 + kc * 8) * N_ + n0 + n;
      bfx8 v;
#pragma unroll
      for (int j = 0; j < 8; ++j) v[j] = (short)f2bf(src[(size_t)j * N_]);
      *(bfx8*)(Bb + n * 128 + ((kc * 16) ^ ((n & 7) << 4))) = v;
    }
    __syncthreads();
#pragma unroll
    for (int kk = 0; kk < 2; ++kk) {
      const int kb = kk * 64 + (lane >> 4) * 16;
      bfx8 af[FM], bfr[FN];
#pragma unroll
      for (int fm = 0; fm < FM; ++fm) {
        int r = wm * WM + fm * 16 + (lane & 15);
        af[fm] = *(const bfx8*)(Ab + r * 128 + (kb ^ ((r & 7) << 4)));
      }
#pragma unroll
      for (int fn = 0; fn < FN; ++fn) {
        int nn = wn * WN + fn * 16 + (lane & 15);
        bfr[fn] = *(const bfx8*)(Bb + nn * 128 + (kb ^ ((nn & 7) << 4)));
      }
#pragma unroll
      for (int fm = 0; fm < FM; ++fm)
#pragma unroll
        for (int fn = 0; fn < FN; ++fn)
          acc[fm][fn] = __builtin_amdgcn_mfma_f32_16x16x32_bf16(
              af[fm], bfr[fn], acc[fm][fn], 0, 0, 0);
    }
    __syncthreads();
  }
  const int colbase = n0 + wn * WN;
  if (FIRST) {
#pragma unroll
    for (int fn = 0; fn < FN; ++fn) {
      int colg = colbase + fn * 16 + (lane & 15);
      float bv = Bias[(size_t)e * N_ + colg];
#pragma unroll
      for (int fm = 0; fm < FM; ++fm) {
        int r = rowbase + wm * WM + fm * 16 + ((lane >> 4) << 2);
#pragma unroll
        for (int j = 0; j < 4; ++j) {
          float v = fmaxf(acc[fm][fn][j] + bv, 0.f);
          Hout[(size_t)(r + j) * F_DIM + colg] = f2bf(v);
        }
      }
    }
  } else {
#pragma unroll
    for (int fm = 0; fm < FM; ++fm) {
      int rb2 = rowbase + wm * WM + fm * 16 + ((lane >> 4) << 2);
#pragma unroll
      for (int j = 0; j < 4; ++j) {
        int tok = perm[rb2 + j];
        if (tok < 0) continue;
        float pm = pmax[tok];
#pragma unroll
        for (int fn = 0; fn < FN; ++fn) {
          int colg = colbase + fn * 16 + (lane & 15);
          float v = (acc[fm][fn][j] + Bias[(size_t)e * N_ + colg]) * pm;
          Out[(size_t)tok * D_DIM + colg] = v;
        }
      }
    }
  }
}

extern "C" void kernel_launch(void* const* d_in, const int* in_sizes, int n_in,
                              void* d_out, int out_size, void* d_ws, size_t ws_size,
                              hipStream_t stream) {
  const float* x  = (const float*)d_in[0];
  const float* sw = (const float*)d_in[1];
  const float* sb = (const float*)d_in[2];
  const float* w1 = (const float*)d_in[3];
  const float* b1 = (const float*)d_in[4];
  const float* w2 = (const float*)d_in[5];
  const float* b2 = (const float*)d_in[6];
  float* out = (float*)d_out;

  char* ws = (char*)d_ws;
  int*   off      = (int*)(ws + 0);          // 9 ints
  int*   counts   = (int*)(ws + 256);        // 8 ints
  int*   cursor   = (int*)(ws + 512);        // 8 ints
  float* psums    = (float*)(ws + 768);      // 8 floats
  int*   routes   = (int*)(ws + 1024);       // 2048 ints
  int*   perm_out = (int*)(ws + 16384);      // RPMAX ints (pads -1)
  int*   perm_src = (int*)(ws + 32768);      // RPMAX ints (pads 0)
  unsigned short* xbf = (unsigned short*)(ws + 65536);        // 2048x1024 bf16 = 4 MB
  unsigned short* H   = (unsigned short*)(ws + (8u << 20));   // RPMAX x 4096 bf16 = 24 MB
  unsigned short* W1T = (unsigned short*)(ws + (40u << 20));  // 8x4096x1024 bf16 = 64 MB
  unsigned short* W2T = (unsigned short*)(ws + (112u << 20)); // 8x1024x4096 bf16 = 64 MB
  const size_t NEED = (176u << 20);

  // d_out layout: final(2097152) | counts(8) | psums(8) | 0(1) | pmax(2048)
  float* out_final  = out;
  float* out_counts = out + 2097152;
  float* out_psums  = out + 2097160;
  float* out_zero   = out + 2097168;
  float* out_pmax   = out + 2097169;

  hipMemsetAsync(ws + 256, 0, 544, stream);             // counts, cursor, psums
  hipMemsetAsync(ws + 16384, 0xFF, RPMAX * 4, stream);  // perm_out = -1
  hipMemsetAsync(ws + 32768, 0x00, RPMAX * 4, stream);  // perm_src = 0

  const bool fast = (ws_size >= NEED);

  router_kernel<<<T_TOK, 64, 0, stream>>>(x, sw, sb, out_pmax, routes, counts, psums,
                                          fast ? xbf : nullptr);
  plan_kernel<<<1, 64, 0, stream>>>(counts, psums, off, out_counts, out_psums, out_zero);
  scatter_kernel<<<(T_TOK + 255) / 256, 256, 0, stream>>>(routes, off, cursor,
                                                          perm_out, perm_src);

  if (fast) {
    // convert + transpose weights to bf16 [E][N][K]
    conv_kernel<D_DIM, F_DIM><<<dim3(F_DIM / 32, D_DIM / 64, E_NUM), 256, 0, stream>>>(w1, W1T);
    conv_kernel<F_DIM, D_DIM><<<dim3(D_DIM / 32, F_DIM / 64, E_NUM), 256, 0, stream>>>(w2, W2T);
    // GEMM1: gather(xbf)[RP,1024] x W1T^T -> H (relu, bf16)
    gemm_fast<D_DIM, F_DIM, true>
        <<<dim3(F_DIM / 128, RPMAX / 128), 256, 0, stream>>>(
            xbf, W1T, b1, off, perm_src, perm_out, nullptr, H, nullptr);
    // GEMM2: H[RP,4096] x W2T^T -> out (bias, *pmax, scatter fp32)
    gemm_fast<F_DIM, D_DIM, false>
        <<<dim3(D_DIM / 128, RPMAX / 128), 256, 0, stream>>>(
            H, W2T, b2, off, perm_src, perm_out, out_pmax, nullptr, out_final);
  } else {
    gemm_kernel<128, 128, 64, 64, 1024, 4096, true>
        <<<dim3(F_DIM / 128, RPMAX / 128), 256, 0, stream>>>(
            x, nullptr, w1, b1, off, perm_out, nullptr, H, nullptr);
    gemm_kernel<64, 128, 32, 64, 4096, 1024, false>
        <<<dim3(D_DIM / 128, RPMAX / 64), 256, 0, stream>>>(
            nullptr, H, w2, b2, off, perm_out, out_pmax, nullptr, out_final);
  }
}

// Round 3
// 239.046 us; speedup vs baseline: 2.6956x; 1.8318x over previous
//
#include <hip/hip_runtime.h>
#include <stdint.h>

// Problem constants (B=2,S=1024,D=1024,F=4096,E=8)
#define T_TOK 2048
#define D_DIM 1024
#define F_DIM 4096
#define E_NUM 8
#define RPMAX 3072   // max padded rows: sum of per-expert ceil(cnt,128) <= 2048+8*127
#define BK 64

typedef __attribute__((ext_vector_type(8))) short bfx8;   // 8 bf16 (4 VGPR)
typedef __attribute__((ext_vector_type(4))) short bfx4;   // 4 bf16 (8B)
typedef __attribute__((ext_vector_type(4))) float fx4;    // MFMA accum

__device__ __forceinline__ unsigned short f2bf(float f) {
  union { float f; uint32_t u; } v; v.f = f;
  uint32_t u = v.u;
  u += 0x7FFFu + ((u >> 16) & 1u);   // round-to-nearest-even
  return (unsigned short)(u >> 16);
}

__device__ __forceinline__ void load_lds16(const unsigned short* g, unsigned short* l) {
  __builtin_amdgcn_global_load_lds(
      (const __attribute__((address_space(1))) void*)g,
      (__attribute__((address_space(3))) void*)l, 16, 0, 0);
}

// ---------------- router: logits, softmax, argmax; NO global atomics ----------------
// 1 wave per token, 4 waves/block. Writes probs[t][8], routes[t], pmax[t], xbf[t][:].
__global__ __launch_bounds__(256) void router_kernel(
    const float* __restrict__ x, const float* __restrict__ sw,
    const float* __restrict__ sb, float* __restrict__ pmax_out,
    int* __restrict__ routes, float* __restrict__ probs,
    unsigned short* __restrict__ xbf) {
  const int wave = threadIdx.x >> 6, lane = threadIdx.x & 63;
  const int t = blockIdx.x * 4 + wave;
  const float* xr = x + (size_t)t * D_DIM;
  float acc[8];
#pragma unroll
  for (int e = 0; e < 8; ++e) acc[e] = 0.f;
#pragma unroll
  for (int i = 0; i < 4; ++i) {
    const int d = i * 256 + lane * 4;
    float4 xv = *(const float4*)(xr + d);
    if (xbf) {
      ushort4 h;
      h.x = f2bf(xv.x); h.y = f2bf(xv.y); h.z = f2bf(xv.z); h.w = f2bf(xv.w);
      *(ushort4*)(xbf + (size_t)t * D_DIM + d) = h;
    }
    const float xs[4] = {xv.x, xv.y, xv.z, xv.w};
#pragma unroll
    for (int j = 0; j < 4; ++j) {
      const float4* swp = (const float4*)(sw + (size_t)(d + j) * 8);
      float4 w0 = swp[0], w1 = swp[1];
      acc[0] += xs[j] * w0.x; acc[1] += xs[j] * w0.y;
      acc[2] += xs[j] * w0.z; acc[3] += xs[j] * w0.w;
      acc[4] += xs[j] * w1.x; acc[5] += xs[j] * w1.y;
      acc[6] += xs[j] * w1.z; acc[7] += xs[j] * w1.w;
    }
  }
#pragma unroll
  for (int e = 0; e < 8; ++e) {
    float v = acc[e];
    for (int o = 32; o > 0; o >>= 1) v += __shfl_down(v, o, 64);
    acc[e] = v;
  }
  if (lane == 0) {
#pragma unroll
    for (int e = 0; e < 8; ++e) acc[e] += sb[e];
    int am = 0; float mx = acc[0];
#pragma unroll
    for (int e = 1; e < 8; ++e) if (acc[e] > mx) { mx = acc[e]; am = e; }  // first-max wins
    float p[8]; float s = 0.f;
#pragma unroll
    for (int e = 0; e < 8; ++e) { p[e] = expf(acc[e] - mx); s += p[e]; }
    float inv = 1.0f / s;
    pmax_out[t] = inv;   // softmax at argmax = exp(0)/s
    routes[t] = am;
#pragma unroll
    for (int e = 0; e < 8; ++e) probs[(size_t)t * 8 + e] = p[e] * inv;
  }
}

// ---------------- plan: counts/psums reduction + 128-aligned offsets ----------------
__global__ __launch_bounds__(256) void plan_kernel(
    const int* __restrict__ routes, const float* __restrict__ probs,
    int* __restrict__ off, float* __restrict__ out_counts,
    float* __restrict__ out_psums, float* __restrict__ out_zero) {
  __shared__ int cnt[8];
  __shared__ float red[256][8];
  const int tid = threadIdx.x;
  if (tid < 8) cnt[tid] = 0;
  __syncthreads();
  float loc[8];
#pragma unroll
  for (int e = 0; e < 8; ++e) loc[e] = 0.f;
  for (int t = tid; t < T_TOK; t += 256) {
    atomicAdd(&cnt[routes[t]], 1);
    const float4* p = (const float4*)(probs + (size_t)t * 8);
    float4 a = p[0], b = p[1];
    loc[0] += a.x; loc[1] += a.y; loc[2] += a.z; loc[3] += a.w;
    loc[4] += b.x; loc[5] += b.y; loc[6] += b.z; loc[7] += b.w;
  }
#pragma unroll
  for (int e = 0; e < 8; ++e) red[tid][e] = loc[e];
  __syncthreads();
  for (int s = 128; s >= 1; s >>= 1) {
    if (tid < s) {
#pragma unroll
      for (int e = 0; e < 8; ++e) red[tid][e] += red[tid + s][e];
    }
    __syncthreads();
  }
  if (tid == 0) {
    int o = 0;
    for (int e = 0; e < 8; ++e) { off[e] = o; o += ((cnt[e] + 127) >> 7) << 7; }
    off[8] = o;
    *out_zero = 0.0f;
  }
  if (tid < 8) {
    out_counts[tid] = (float)cnt[tid];
    out_psums[tid] = red[0][tid];
  }
}

// ---------------- scatter: token -> gathered slot ----------------
__global__ __launch_bounds__(256) void scatter_kernel(
    const int* __restrict__ routes, const int* __restrict__ off,
    int* __restrict__ cursor, int* __restrict__ perm_out,
    int* __restrict__ perm_src) {
  int t = blockIdx.x * 256 + threadIdx.x;
  if (t >= T_TOK) return;
  int e = routes[t];
  int pos = atomicAdd(&cursor[e], 1);
  perm_out[off[e] + pos] = t;
  perm_src[off[e] + pos] = t;
}

// ---------------- convert+transpose: W fp32 [E][K][N] -> bf16 [E][N][K] ----------------
template <int K_, int N_>
__global__ __launch_bounds__(256) void conv_kernel(
    const float* __restrict__ W, unsigned short* __restrict__ WT) {
  __shared__ unsigned short tile[64][34];   // [k][n], pad to 34 u16 (68B rows)
  const int t = threadIdx.x;
  const int nbase = blockIdx.x * 32;
  const int kbase = blockIdx.y * 64;
  const int e = blockIdx.z;
  const float* We = W + (size_t)e * K_ * N_;
  unsigned short* WTe = WT + (size_t)e * N_ * K_;
  // phase 1: read 64k x 32n fp32 coalesced, convert, store LDS [k][n]
  {
    int kl = t >> 2;               // 0..63
    int nc = (t & 3) * 8;          // 0..24 step 8
    const float4* src = (const float4*)(We + (size_t)(kbase + kl) * N_ + nbase + nc);
    float4 a = src[0], b = src[1];
    unsigned short u[8] = {f2bf(a.x), f2bf(a.y), f2bf(a.z), f2bf(a.w),
                           f2bf(b.x), f2bf(b.y), f2bf(b.z), f2bf(b.w)};
#pragma unroll
    for (int p = 0; p < 4; ++p) {
      uint32_t pk = (uint32_t)u[2 * p] | ((uint32_t)u[2 * p + 1] << 16);
      *(uint32_t*)&tile[kl][nc + 2 * p] = pk;
    }
  }
  __syncthreads();
  // phase 2: write 32n x 64k bf16 coalesced along k
  {
    int nl = t >> 3;               // 0..31
    int kc = (t & 7) * 8;          // 0..56 step 8
    bfx8 v;
#pragma unroll
    for (int i = 0; i < 8; ++i) v[i] = (short)tile[kc + i][nl];
    *(bfx8*)(WTe + (size_t)(nbase + nl) * K_ + kbase + kc) = v;
  }
}

// ---------------- fast grouped GEMM (bf16 x bf16-transposed weights) ----------------
template <int K_, int N_, bool FIRST>
__global__ __launch_bounds__(256) void gemm_fast(
    const unsigned short* __restrict__ A,    // FIRST: xbf [T][K_]; else H [RP][K_]
    const unsigned short* __restrict__ WT,   // [E][N_][K_] bf16
    const float* __restrict__ Bias,          // [E][N_]
    const int* __restrict__ off,
    const int* __restrict__ perm_src, const int* __restrict__ perm_out,
    const float* __restrict__ pmax,
    unsigned short* __restrict__ Hout, float* __restrict__ Out) {
  __shared__ __align__(16) unsigned short As[128 * 64];
  __shared__ __align__(16) unsigned short Bs[128 * 64];
  const int tid = threadIdx.x;
  const int rowbase = blockIdx.y * 128;
  if (rowbase >= off[8]) return;
  int e = 0;
#pragma unroll
  for (int i = 1; i <= 7; ++i) if (rowbase >= off[i]) e = i;
  const int n0 = blockIdx.x * 128;
  const int wave = tid >> 6, lane = tid & 63;
  const int wm = wave >> 1, wn = wave & 1;

  // per-lane pre-swizzled global source pointers (m173): LDS stays linear,
  // source chunk index XOR'd so swizzled ds_reads retrieve logical data.
  const unsigned short* aSrc[4];
  const unsigned short* bSrc[4];
#pragma unroll
  for (int c = 0; c < 4; ++c) {
    int ca = (wave * 4 + c) * 64 + lane;      // 16B-chunk id, 0..1023
    int row = ca >> 3, slot = ca & 7;
    int sc = slot ^ (row & 7);
    size_t arow = FIRST ? (size_t)perm_src[rowbase + row] : (size_t)(rowbase + row);
    aSrc[c] = A + arow * K_ + sc * 8;
    bSrc[c] = WT + ((size_t)e * N_ + (n0 + row)) * (size_t)K_ + sc * 8;
  }
  unsigned short* aDst = As + wave * 2048;    // 4 chunks x 512 u16 per wave
  unsigned short* bDst = Bs + wave * 2048;

  fx4 acc[4][4];
#pragma unroll
  for (int a = 0; a < 4; ++a)
#pragma unroll
    for (int b = 0; b < 4; ++b) acc[a][b] = (fx4){0.f, 0.f, 0.f, 0.f};

  for (int k0 = 0; k0 < K_; k0 += BK) {
#pragma unroll
    for (int c = 0; c < 4; ++c) {
      load_lds16(aSrc[c] + k0, aDst + c * 512);
      load_lds16(bSrc[c] + k0, bDst + c * 512);
    }
    __syncthreads();
#pragma unroll
    for (int kk = 0; kk < 2; ++kk) {
      bfx8 af[4], bf[4];
#pragma unroll
      for (int fm = 0; fm < 4; ++fm) {
        int r = wm * 64 + fm * 16 + (lane & 15);
        int chunk = (kk * 4 + (lane >> 4)) ^ (r & 7);
        af[fm] = *(const bfx8*)(As + r * 64 + chunk * 8);
      }
#pragma unroll
      for (int fn = 0; fn < 4; ++fn) {
        int nn = wn * 64 + fn * 16 + (lane & 15);
        int chunk = (kk * 4 + (lane >> 4)) ^ (nn & 7);
        bf[fn] = *(const bfx8*)(Bs + nn * 64 + chunk * 8);
      }
#pragma unroll
      for (int fm = 0; fm < 4; ++fm)
#pragma unroll
        for (int fn = 0; fn < 4; ++fn)
          acc[fm][fn] = __builtin_amdgcn_mfma_f32_16x16x32_bf16(
              af[fm], bf[fn], acc[fm][fn], 0, 0, 0);
    }
    __syncthreads();
  }

  const int colbase = n0 + wn * 64;
  if (FIRST) {
#pragma unroll
    for (int fn = 0; fn < 4; ++fn) {
      int colg = colbase + fn * 16 + (lane & 15);
      float bv = Bias[(size_t)e * N_ + colg];
#pragma unroll
      for (int fm = 0; fm < 4; ++fm) {
        int rg = rowbase + wm * 64 + fm * 16 + ((lane >> 4) << 2);
#pragma unroll
        for (int j = 0; j < 4; ++j) {
          float v = fmaxf(acc[fm][fn][j] + bv, 0.f);
          Hout[(size_t)(rg + j) * N_ + colg] = f2bf(v);
        }
      }
    }
  } else {
#pragma unroll
    for (int fm = 0; fm < 4; ++fm) {
      int rg = rowbase + wm * 64 + fm * 16 + ((lane >> 4) << 2);
#pragma unroll
      for (int j = 0; j < 4; ++j) {
        int tok = perm_out[rg + j];
        if (tok < 0) continue;
        float pm = pmax[tok];
#pragma unroll
        for (int fn = 0; fn < 4; ++fn) {
          int colg = colbase + fn * 16 + (lane & 15);
          Out[(size_t)tok * N_ + colg] = (acc[fm][fn][j] + Bias[(size_t)e * N_ + colg]) * pm;
        }
      }
    }
  }
}

// ---------------- fallback grouped GEMM (fp32 weights in-loop) ----------------
template <int BM, int BN, int WM, int WN, int K_, int N_, bool FIRST>
__global__ __launch_bounds__(256) void gemm_kernel(
    const float* __restrict__ X, const unsigned short* __restrict__ Hin,
    const float* __restrict__ W, const float* __restrict__ Bias,
    const int* __restrict__ off, const int* __restrict__ perm,
    const float* __restrict__ pmax, unsigned short* __restrict__ Hout,
    float* __restrict__ Out) {
  constexpr int FM = WM / 16, FN = WN / 16;
  constexpr int WAVES_N = BN / WN;
  __shared__ unsigned short As[BM * BK];
  __shared__ unsigned short Bs[BN * BK];
  const int tid = threadIdx.x;
  const int rowbase = blockIdx.y * BM;
  if (rowbase >= off[8]) return;
  int e = 0;
#pragma unroll
  for (int i = 1; i <= 7; ++i) if (rowbase >= off[i]) e = i;
  const int n0 = blockIdx.x * BN;
  const float* We = W + (size_t)e * K_ * N_;
  const int wave = tid >> 6, lane = tid & 63;
  const int wm = wave / WAVES_N, wn = wave % WAVES_N;
  char* Ab = (char*)As;
  char* Bb = (char*)Bs;
  fx4 acc[FM][FN];
#pragma unroll
  for (int a = 0; a < FM; ++a)
#pragma unroll
    for (int b = 0; b < FN; ++b) acc[a][b] = (fx4){0.f, 0.f, 0.f, 0.f};
  for (int k0 = 0; k0 < K_; k0 += BK) {
    if (FIRST) {
#pragma unroll
      for (int it = 0; it < BM / 16; ++it) {
        int id = it * 256 + tid;
        int row = id >> 4, kq = id & 15;
        int tok = perm[rowbase + row];
        float4 v = make_float4(0.f, 0.f, 0.f, 0.f);
        if (tok >= 0) v = *(const float4*)(X + (size_t)tok * D_DIM + k0 + kq * 4);
        bfx4 h;
        h.x = (short)f2bf(v.x); h.y = (short)f2bf(v.y);
        h.z = (short)f2bf(v.z); h.w = (short)f2bf(v.w);
        *(bfx4*)(Ab + row * 128 + ((kq * 8) ^ ((row & 7) << 4))) = h;
      }
    } else {
#pragma unroll
      for (int it = 0; it < BM / 32; ++it) {
        int id = it * 256 + tid;
        int row = id >> 3, kq = id & 7;
        bfx8 v = *(const bfx8*)(Hin + (size_t)(rowbase + row) * F_DIM + k0 + kq * 8);
        *(bfx8*)(Ab + row * 128 + ((kq * 16) ^ ((row & 7) << 4))) = v;
      }
    }
#pragma unroll
    for (int it = 0; it < BN / 32; ++it) {
      int c = it * 256 + tid;
      int n = c & (BN - 1);
      int kc = c / BN;
      const float* src = We + (size_t)(k0 + kc * 8) * N_ + n0 + n;
      bfx8 v;
#pragma unroll
      for (int j = 0; j < 8; ++j) v[j] = (short)f2bf(src[(size_t)j * N_]);
      *(bfx8*)(Bb + n * 128 + ((kc * 16) ^ ((n & 7) << 4))) = v;
    }
    __syncthreads();
#pragma unroll
    for (int kk = 0; kk < 2; ++kk) {
      const int kb = kk * 64 + (lane >> 4) * 16;
      bfx8 af[FM], bfr[FN];
#pragma unroll
      for (int fm = 0; fm < FM; ++fm) {
        int r = wm * WM + fm * 16 + (lane & 15);
        af[fm] = *(const bfx8*)(Ab + r * 128 + (kb ^ ((r & 7) << 4)));
      }
#pragma unroll
      for (int fn = 0; fn < FN; ++fn) {
        int nn = wn * WN + fn * 16 + (lane & 15);
        bfr[fn] = *(const bfx8*)(Bb + nn * 128 + (kb ^ ((nn & 7) << 4)));
      }
#pragma unroll
      for (int fm = 0; fm < FM; ++fm)
#pragma unroll
        for (int fn = 0; fn < FN; ++fn)
          acc[fm][fn] = __builtin_amdgcn_mfma_f32_16x16x32_bf16(
              af[fm], bfr[fn], acc[fm][fn], 0, 0, 0);
    }
    __syncthreads();
  }
  const int colbase = n0 + wn * WN;
  if (FIRST) {
#pragma unroll
    for (int fn = 0; fn < FN; ++fn) {
      int colg = colbase + fn * 16 + (lane & 15);
      float bv = Bias[(size_t)e * N_ + colg];
#pragma unroll
      for (int fm = 0; fm < FM; ++fm) {
        int r = rowbase + wm * WM + fm * 16 + ((lane >> 4) << 2);
#pragma unroll
        for (int j = 0; j < 4; ++j) {
          float v = fmaxf(acc[fm][fn][j] + bv, 0.f);
          Hout[(size_t)(r + j) * F_DIM + colg] = f2bf(v);
        }
      }
    }
  } else {
#pragma unroll
    for (int fm = 0; fm < FM; ++fm) {
      int rb2 = rowbase + wm * WM + fm * 16 + ((lane >> 4) << 2);
#pragma unroll
      for (int j = 0; j < 4; ++j) {
        int tok = perm[rb2 + j];
        if (tok < 0) continue;
        float pm = pmax[tok];
#pragma unroll
        for (int fn = 0; fn < FN; ++fn) {
          int colg = colbase + fn * 16 + (lane & 15);
          float v = (acc[fm][fn][j] + Bias[(size_t)e * N_ + colg]) * pm;
          Out[(size_t)tok * D_DIM + colg] = v;
        }
      }
    }
  }
}

extern "C" void kernel_launch(void* const* d_in, const int* in_sizes, int n_in,
                              void* d_out, int out_size, void* d_ws, size_t ws_size,
                              hipStream_t stream) {
  const float* x  = (const float*)d_in[0];
  const float* sw = (const float*)d_in[1];
  const float* sb = (const float*)d_in[2];
  const float* w1 = (const float*)d_in[3];
  const float* b1 = (const float*)d_in[4];
  const float* w2 = (const float*)d_in[5];
  const float* b2 = (const float*)d_in[6];
  float* out = (float*)d_out;

  char* ws = (char*)d_ws;
  int*   off      = (int*)(ws + 0);          // 9 ints
  int*   cursor   = (int*)(ws + 512);        // 8 ints
  int*   routes   = (int*)(ws + 1024);       // 2048 ints
  int*   perm_out = (int*)(ws + 16384);      // RPMAX ints (pads -1)
  int*   perm_src = (int*)(ws + 32768);      // RPMAX ints (pads 0)
  float* probs    = (float*)(ws + 49152);    // 2048x8 fp32 = 64 KB
  unsigned short* xbf = (unsigned short*)(ws + (1u << 20));   // 2048x1024 bf16 = 4 MB
  unsigned short* H   = (unsigned short*)(ws + (8u << 20));   // RPMAX x 4096 bf16 = 24 MB
  unsigned short* W1T = (unsigned short*)(ws + (40u << 20));  // 8x4096x1024 bf16 = 64 MB
  unsigned short* W2T = (unsigned short*)(ws + (112u << 20)); // 8x1024x4096 bf16 = 64 MB
  const size_t NEED = (176u << 20);

  // d_out layout: final(2097152) | counts(8) | psums(8) | 0(1) | pmax(2048)
  float* out_final  = out;
  float* out_counts = out + 2097152;
  float* out_psums  = out + 2097160;
  float* out_zero   = out + 2097168;
  float* out_pmax   = out + 2097169;

  hipMemsetAsync(ws + 512, 0, 64, stream);              // cursor
  hipMemsetAsync(ws + 16384, 0xFF, RPMAX * 4, stream);  // perm_out = -1
  hipMemsetAsync(ws + 32768, 0x00, RPMAX * 4, stream);  // perm_src = 0

  const bool fast = (ws_size >= NEED);

  router_kernel<<<T_TOK / 4, 256, 0, stream>>>(x, sw, sb, out_pmax, routes, probs,
                                               fast ? xbf : nullptr);
  plan_kernel<<<1, 256, 0, stream>>>(routes, probs, off, out_counts, out_psums, out_zero);
  scatter_kernel<<<(T_TOK + 255) / 256, 256, 0, stream>>>(routes, off, cursor,
                                                          perm_out, perm_src);

  if (fast) {
    conv_kernel<D_DIM, F_DIM><<<dim3(F_DIM / 32, D_DIM / 64, E_NUM), 256, 0, stream>>>(w1, W1T);
    conv_kernel<F_DIM, D_DIM><<<dim3(D_DIM / 32, F_DIM / 64, E_NUM), 256, 0, stream>>>(w2, W2T);
    gemm_fast<D_DIM, F_DIM, true>
        <<<dim3(F_DIM / 128, RPMAX / 128), 256, 0, stream>>>(
            xbf, W1T, b1, off, perm_src, perm_out, nullptr, H, nullptr);
    gemm_fast<F_DIM, D_DIM, false>
        <<<dim3(D_DIM / 128, RPMAX / 128), 256, 0, stream>>>(
            H, W2T, b2, off, perm_src, perm_out, out_pmax, nullptr, out_final);
  } else {
    gemm_kernel<128, 128, 64, 64, 1024, 4096, true>
        <<<dim3(F_DIM / 128, RPMAX / 128), 256, 0, stream>>>(
            x, nullptr, w1, b1, off, perm_out, nullptr, H, nullptr);
    gemm_kernel<64, 128, 32, 64, 4096, 1024, false>
        <<<dim3(D_DIM / 128, RPMAX / 64), 256, 0, stream>>>(
            nullptr, H, w2, b2, off, perm_out, out_pmax, nullptr, out_final);
  }
}

// Round 4
// 231.431 us; speedup vs baseline: 2.7843x; 1.0329x over previous
//
#include <hip/hip_runtime.h>
#include <stdint.h>

// Problem constants (B=2,S=1024,D=1024,F=4096,E=8)
#define T_TOK 2048
#define D_DIM 1024
#define F_DIM 4096
#define E_NUM 8
#define RPMAX 3072   // max padded rows: sum of per-expert ceil(cnt,128) <= 2048+8*127
#define BK 64

typedef __attribute__((ext_vector_type(8))) short bfx8;   // 8 bf16 (4 VGPR)
typedef __attribute__((ext_vector_type(4))) float fx4;    // MFMA accum / staging

__device__ __forceinline__ unsigned short f2bf(float f) {
  union { float f; uint32_t u; } v; v.f = f;
  uint32_t u = v.u;
  u += 0x7FFFu + ((u >> 16) & 1u);   // round-to-nearest-even
  return (unsigned short)(u >> 16);
}

__device__ __forceinline__ void load_lds16(const unsigned short* g, unsigned short* l) {
  __builtin_amdgcn_global_load_lds(
      (const __attribute__((address_space(1))) void*)g,
      (__attribute__((address_space(3))) void*)l, 16, 0, 0);
}

__device__ __forceinline__ uint32_t cvtpk_bf16(float lo, float hi) {
  uint32_t d;
  asm("v_cvt_pk_bf16_f32 %0, %1, %2" : "=v"(d) : "v"(lo), "v"(hi));
  return d;
}

// ---------------- router: logits, softmax, argmax; NO global atomics ----------------
__global__ __launch_bounds__(256) void router_kernel(
    const float* __restrict__ x, const float* __restrict__ sw,
    const float* __restrict__ sb, float* __restrict__ pmax_out,
    int* __restrict__ routes, float* __restrict__ probs,
    unsigned short* __restrict__ xbf) {
  const int wave = threadIdx.x >> 6, lane = threadIdx.x & 63;
  const int t = blockIdx.x * 4 + wave;
  const float* xr = x + (size_t)t * D_DIM;
  float acc[8];
#pragma unroll
  for (int e = 0; e < 8; ++e) acc[e] = 0.f;
#pragma unroll
  for (int i = 0; i < 4; ++i) {
    const int d = i * 256 + lane * 4;
    float4 xv = *(const float4*)(xr + d);
    ushort4 h;
    h.x = f2bf(xv.x); h.y = f2bf(xv.y); h.z = f2bf(xv.z); h.w = f2bf(xv.w);
    *(ushort4*)(xbf + (size_t)t * D_DIM + d) = h;
    const float xs[4] = {xv.x, xv.y, xv.z, xv.w};
#pragma unroll
    for (int j = 0; j < 4; ++j) {
      const float4* swp = (const float4*)(sw + (size_t)(d + j) * 8);
      float4 w0 = swp[0], w1 = swp[1];
      acc[0] += xs[j] * w0.x; acc[1] += xs[j] * w0.y;
      acc[2] += xs[j] * w0.z; acc[3] += xs[j] * w0.w;
      acc[4] += xs[j] * w1.x; acc[5] += xs[j] * w1.y;
      acc[6] += xs[j] * w1.z; acc[7] += xs[j] * w1.w;
    }
  }
#pragma unroll
  for (int e = 0; e < 8; ++e) {
    float v = acc[e];
    for (int o = 32; o > 0; o >>= 1) v += __shfl_down(v, o, 64);
    acc[e] = v;
  }
  if (lane == 0) {
#pragma unroll
    for (int e = 0; e < 8; ++e) acc[e] += sb[e];
    int am = 0; float mx = acc[0];
#pragma unroll
    for (int e = 1; e < 8; ++e) if (acc[e] > mx) { mx = acc[e]; am = e; }  // first-max wins
    float p[8]; float s = 0.f;
#pragma unroll
    for (int e = 0; e < 8; ++e) { p[e] = expf(acc[e] - mx); s += p[e]; }
    float inv = 1.0f / s;
    pmax_out[t] = inv;
    routes[t] = am;
#pragma unroll
    for (int e = 0; e < 8; ++e) probs[(size_t)t * 8 + e] = p[e] * inv;
  }
}

// ---------------- plan: counts/psums reduction + 128-aligned offsets ----------------
__global__ __launch_bounds__(256) void plan_kernel(
    const int* __restrict__ routes, const float* __restrict__ probs,
    int* __restrict__ off, float* __restrict__ out_counts,
    float* __restrict__ out_psums, float* __restrict__ out_zero) {
  __shared__ int cnt[8];
  __shared__ float red[256][8];
  const int tid = threadIdx.x;
  if (tid < 8) cnt[tid] = 0;
  __syncthreads();
  float loc[8];
#pragma unroll
  for (int e = 0; e < 8; ++e) loc[e] = 0.f;
  for (int t = tid; t < T_TOK; t += 256) {
    atomicAdd(&cnt[routes[t]], 1);
    const float4* p = (const float4*)(probs + (size_t)t * 8);
    float4 a = p[0], b = p[1];
    loc[0] += a.x; loc[1] += a.y; loc[2] += a.z; loc[3] += a.w;
    loc[4] += b.x; loc[5] += b.y; loc[6] += b.z; loc[7] += b.w;
  }
#pragma unroll
  for (int e = 0; e < 8; ++e) red[tid][e] = loc[e];
  __syncthreads();
  for (int s = 128; s >= 1; s >>= 1) {
    if (tid < s) {
#pragma unroll
      for (int e = 0; e < 8; ++e) red[tid][e] += red[tid + s][e];
    }
    __syncthreads();
  }
  if (tid == 0) {
    int o = 0;
    for (int e = 0; e < 8; ++e) { off[e] = o; o += ((cnt[e] + 127) >> 7) << 7; }
    off[8] = o;
    *out_zero = 0.0f;
  }
  if (tid < 8) {
    out_counts[tid] = (float)cnt[tid];
    out_psums[tid] = red[0][tid];
  }
}

// ---------------- scatter: token -> gathered slot ----------------
__global__ __launch_bounds__(256) void scatter_kernel(
    const int* __restrict__ routes, const int* __restrict__ off,
    int* __restrict__ cursor, int* __restrict__ perm_out,
    int* __restrict__ perm_src) {
  int t = blockIdx.x * 256 + threadIdx.x;
  if (t >= T_TOK) return;
  int e = routes[t];
  int pos = atomicAdd(&cursor[e], 1);
  perm_out[off[e] + pos] = t;
  perm_src[off[e] + pos] = t;
}

// ---------------- fused grouped GEMM: bf16 A x fp32 W (in-loop convert) ----------------
// 128x128 tile, BK=64, 4 waves. A bf16 via global_load_lds (pre-swizzled src).
// B: W[e] fp32 [K][N] -> coalesced float4 -> cvt_pk bf16 -> reg 4x4 transpose ->
//    swizzled ds_write_b64 into [n][k] LDS. Double-buffered, 1 barrier / K-step.
// NCHUNK: XCD swizzle chunks by n (GEMM1) or by m (GEMM2).
template <int K_, int N_, bool FIRST, bool NCHUNK>
__global__ __launch_bounds__(256) void gemm_fused(
    const unsigned short* __restrict__ A,    // FIRST: xbf [T][K_]; else H [RP][K_]
    const float* __restrict__ W,             // [E][K_][N_] fp32
    const float* __restrict__ Bias,          // [E][N_]
    const int* __restrict__ off,
    const int* __restrict__ perm_src, const int* __restrict__ perm_out,
    const float* __restrict__ pmax,
    unsigned short* __restrict__ Hout, float* __restrict__ Out) {
  __shared__ __align__(16) unsigned short As[2][128 * 64];
  __shared__ __align__(16) unsigned short Bs[2][128 * 64];
  const int tid = threadIdx.x;
  // XCD-chunked bijective swizzle (grid sizes are multiples of 8)
  const int nbx = gridDim.x, nby = gridDim.y;
  const int lin = blockIdx.y * nbx + blockIdx.x;
  const int chunk = (nbx * nby) >> 3;
  const int newlin = (lin & 7) * chunk + (lin >> 3);
  const int bx = NCHUNK ? (newlin / nby) : (newlin % nbx);
  const int by = NCHUNK ? (newlin % nby) : (newlin / nbx);
  const int rowbase = by * 128;
  if (rowbase >= off[8]) return;
  int e = 0;
#pragma unroll
  for (int i = 1; i <= 7; ++i) if (rowbase >= off[i]) e = i;
  const int n0 = bx * 128;
  const int wave = tid >> 6, lane = tid & 63;
  const int wm = wave >> 1, wn = wave & 1;
  const float* Wn0 = W + (size_t)e * K_ * N_ + n0;

  // A: per-lane pre-swizzled global sources (m173): LDS linear, src chunk XOR'd.
  const unsigned short* aSrc[4];
#pragma unroll
  for (int c = 0; c < 4; ++c) {
    int ca = (wave * 4 + c) * 64 + lane;      // 16B-chunk id, 0..1023
    int row = ca >> 3, slot = ca & 7;
    int sc = slot ^ (row & 7);
    size_t arow = FIRST ? (size_t)perm_src[rowbase + row] : (size_t)(rowbase + row);
    aSrc[c] = A + arow * K_ + sc * 8;
  }

  fx4 breg[2][4];     // [q2][j] staged fp32 B values (4x4 micro-tile pair)
  const int qbase = (lane >> 5) * 2;
  const int nq = lane & 31;

  auto B_LOAD = [&](int kt) {
#pragma unroll
    for (int q2 = 0; q2 < 2; ++q2) {
      const int q = qbase + q2;
#pragma unroll
      for (int j = 0; j < 4; ++j)
        breg[q2][j] = *(const fx4*)(Wn0 + (size_t)(kt + wave * 16 + q * 4 + j) * N_ + nq * 4);
    }
  };
  auto B_STORE = [&](unsigned short* Bsb) {
#pragma unroll
    for (int q2 = 0; q2 < 2; ++q2) {
      const int q = qbase + q2;
      const int c16 = wave * 2 + (q >> 1);
      const int off8 = (q & 1) * 8;
#pragma unroll
      for (int i = 0; i < 4; ++i) {
        const int nl = nq * 4 + i;
        uint32_t d0 = cvtpk_bf16(breg[q2][0][i], breg[q2][1][i]);
        uint32_t d1 = cvtpk_bf16(breg[q2][2][i], breg[q2][3][i]);
        *(uint2*)((char*)Bsb + nl * 128 + ((c16 ^ (nl & 7)) * 16) + off8) =
            make_uint2(d0, d1);
      }
    }
  };
  auto A_STAGE = [&](int kt, unsigned short* Asb) {
#pragma unroll
    for (int c = 0; c < 4; ++c)
      load_lds16(aSrc[c] + kt, Asb + (wave * 4 + c) * 512);
  };

  fx4 acc[4][4];
#pragma unroll
  for (int a = 0; a < 4; ++a)
#pragma unroll
    for (int b = 0; b < 4; ++b) acc[a][b] = (fx4){0.f, 0.f, 0.f, 0.f};

  // prologue: stage tile 0 into buf 0
  A_STAGE(0, As[0]);
  B_LOAD(0);
  B_STORE(Bs[0]);
  __syncthreads();

  int cur = 0;
  for (int k0 = 0; k0 < K_; k0 += BK) {
    const bool nxt = (k0 + BK) < K_;
    if (nxt) {
      A_STAGE(k0 + BK, As[cur ^ 1]);   // async DMA into other buffer
      B_LOAD(k0 + BK);                 // global -> regs, latency hidden by MFMA
    }
    // compute tile k0 from buf cur
#pragma unroll
    for (int kk = 0; kk < 2; ++kk) {
      bfx8 af[4], bf[4];
#pragma unroll
      for (int fm = 0; fm < 4; ++fm) {
        int r = wm * 64 + fm * 16 + (lane & 15);
        int c = (kk * 4 + (lane >> 4)) ^ (r & 7);
        af[fm] = *(const bfx8*)(&As[cur][r * 64 + c * 8]);
      }
#pragma unroll
      for (int fn = 0; fn < 4; ++fn) {
        int nn = wn * 64 + fn * 16 + (lane & 15);
        int c = (kk * 4 + (lane >> 4)) ^ (nn & 7);
        bf[fn] = *(const bfx8*)(&Bs[cur][nn * 64 + c * 8]);
      }
#pragma unroll
      for (int fm = 0; fm < 4; ++fm)
#pragma unroll
        for (int fn = 0; fn < 4; ++fn)
          acc[fm][fn] = __builtin_amdgcn_mfma_f32_16x16x32_bf16(
              af[fm], bf[fn], acc[fm][fn], 0, 0, 0);
    }
    if (nxt) B_STORE(Bs[cur ^ 1]);     // cvt + write other buffer (post-MFMA)
    __syncthreads();                   // one barrier per K-step
    cur ^= 1;
  }

  // ---- epilogue ----
  const int colbase = n0 + wn * 64;
  if (FIRST) {
#pragma unroll
    for (int fn = 0; fn < 4; ++fn) {
      int colg = colbase + fn * 16 + (lane & 15);
      float bv = Bias[(size_t)e * N_ + colg];
#pragma unroll
      for (int fm = 0; fm < 4; ++fm) {
        int rg = rowbase + wm * 64 + fm * 16 + ((lane >> 4) << 2);
#pragma unroll
        for (int j = 0; j < 4; ++j) {
          float v = fmaxf(acc[fm][fn][j] + bv, 0.f);
          Hout[(size_t)(rg + j) * N_ + colg] = f2bf(v);
        }
      }
    }
  } else {
#pragma unroll
    for (int fm = 0; fm < 4; ++fm) {
      int rg = rowbase + wm * 64 + fm * 16 + ((lane >> 4) << 2);
#pragma unroll
      for (int j = 0; j < 4; ++j) {
        int tok = perm_out[rg + j];
        if (tok < 0) continue;
        float pm = pmax[tok];
#pragma unroll
        for (int fn = 0; fn < 4; ++fn) {
          int colg = colbase + fn * 16 + (lane & 15);
          Out[(size_t)tok * N_ + colg] = (acc[fm][fn][j] + Bias[(size_t)e * N_ + colg]) * pm;
        }
      }
    }
  }
}

extern "C" void kernel_launch(void* const* d_in, const int* in_sizes, int n_in,
                              void* d_out, int out_size, void* d_ws, size_t ws_size,
                              hipStream_t stream) {
  const float* x  = (const float*)d_in[0];
  const float* sw = (const float*)d_in[1];
  const float* sb = (const float*)d_in[2];
  const float* w1 = (const float*)d_in[3];
  const float* b1 = (const float*)d_in[4];
  const float* w2 = (const float*)d_in[5];
  const float* b2 = (const float*)d_in[6];
  float* out = (float*)d_out;

  char* ws = (char*)d_ws;
  int*   off      = (int*)(ws + 0);          // 9 ints
  int*   cursor   = (int*)(ws + 512);        // 8 ints
  int*   routes   = (int*)(ws + 1024);       // 2048 ints
  int*   perm_out = (int*)(ws + 16384);      // RPMAX ints (pads -1)
  int*   perm_src = (int*)(ws + 32768);      // RPMAX ints (pads 0)
  float* probs    = (float*)(ws + 49152);    // 2048x8 fp32
  unsigned short* xbf = (unsigned short*)(ws + (1u << 20));   // 4 MB
  unsigned short* H   = (unsigned short*)(ws + (8u << 20));   // RPMAX x 4096 bf16 = 24 MB

  // d_out layout: final(2097152) | counts(8) | psums(8) | 0(1) | pmax(2048)
  float* out_final  = out;
  float* out_counts = out + 2097152;
  float* out_psums  = out + 2097160;
  float* out_zero   = out + 2097168;
  float* out_pmax   = out + 2097169;

  hipMemsetAsync(ws + 512, 0, 64, stream);              // cursor
  hipMemsetAsync(ws + 16384, 0xFF, RPMAX * 4, stream);  // perm_out = -1
  hipMemsetAsync(ws + 32768, 0x00, RPMAX * 4, stream);  // perm_src = 0

  router_kernel<<<T_TOK / 4, 256, 0, stream>>>(x, sw, sb, out_pmax, routes, probs, xbf);
  plan_kernel<<<1, 256, 0, stream>>>(routes, probs, off, out_counts, out_psums, out_zero);
  scatter_kernel<<<(T_TOK + 255) / 256, 256, 0, stream>>>(routes, off, cursor,
                                                          perm_out, perm_src);

  // GEMM1: gather(xbf)[RP,1024] x W1 -> H (relu, bf16). n-chunked XCD swizzle.
  gemm_fused<D_DIM, F_DIM, true, true>
      <<<dim3(F_DIM / 128, RPMAX / 128), 256, 0, stream>>>(
          xbf, w1, b1, off, perm_src, perm_out, nullptr, H, nullptr);
  // GEMM2: H[RP,4096] x W2 -> out (bias, *pmax, scatter fp32). m-chunked swizzle.
  gemm_fused<F_DIM, D_DIM, false, false>
      <<<dim3(D_DIM / 128, RPMAX / 128), 256, 0, stream>>>(
          H, w2, b2, off, perm_src, perm_out, out_pmax, nullptr, out_final);
}

// Round 5
// 185.545 us; speedup vs baseline: 3.4728x; 1.2473x over previous
//
#include <hip/hip_runtime.h>
#include <stdint.h>

// Problem constants (B=2,S=1024,D=1024,F=4096,E=8)
#define T_TOK 2048
#define D_DIM 1024
#define F_DIM 4096
#define E_NUM 8
#define RPMAX 3072   // max padded rows: sum of per-expert ceil(cnt,128)
#define BK 64

typedef __attribute__((ext_vector_type(8))) short bfx8;   // 8 bf16 (4 VGPR)
typedef __attribute__((ext_vector_type(4))) float fx4;    // MFMA accum / staging

__device__ __forceinline__ unsigned short f2bf(float f) {
  union { float f; uint32_t u; } v; v.f = f;
  uint32_t u = v.u;
  u += 0x7FFFu + ((u >> 16) & 1u);   // round-to-nearest-even
  return (unsigned short)(u >> 16);
}

__device__ __forceinline__ void load_lds16(const unsigned short* g, unsigned short* l) {
  __builtin_amdgcn_global_load_lds(
      (const __attribute__((address_space(1))) void*)g,
      (__attribute__((address_space(3))) void*)l, 16, 0, 0);
}

__device__ __forceinline__ uint32_t cvtpk_bf16(float lo, float hi) {
  uint32_t d;
  asm("v_cvt_pk_bf16_f32 %0, %1, %2" : "=v"(d) : "v"(lo), "v"(hi));
  return d;
}

template <int N>
__device__ __forceinline__ void vm_wait() {
  if constexpr (N == 0)  asm volatile("s_waitcnt vmcnt(0)" ::: "memory");
  else if constexpr (N == 4)  asm volatile("s_waitcnt vmcnt(4)" ::: "memory");
  else if constexpr (N == 8)  asm volatile("s_waitcnt vmcnt(8)" ::: "memory");
  else if constexpr (N == 12) asm volatile("s_waitcnt vmcnt(12)" ::: "memory");
  else if constexpr (N == 16) asm volatile("s_waitcnt vmcnt(16)" ::: "memory");
}
template <int N>
__device__ __forceinline__ void vm_wait_lgkm() {
  if constexpr (N == 0) asm volatile("s_waitcnt vmcnt(0) lgkmcnt(0)" ::: "memory");
  else if constexpr (N == 4) asm volatile("s_waitcnt vmcnt(4) lgkmcnt(0)" ::: "memory");
  else if constexpr (N == 8) asm volatile("s_waitcnt vmcnt(8) lgkmcnt(0)" ::: "memory");
}

// ---------------- router: logits, softmax, argmax; NO global atomics ----------------
__global__ __launch_bounds__(256) void router_kernel(
    const float* __restrict__ x, const float* __restrict__ sw,
    const float* __restrict__ sb, float* __restrict__ pmax_out,
    int* __restrict__ routes, float* __restrict__ probs,
    unsigned short* __restrict__ xbf) {
  const int wave = threadIdx.x >> 6, lane = threadIdx.x & 63;
  const int t = blockIdx.x * 4 + wave;
  const float* xr = x + (size_t)t * D_DIM;
  float acc[8];
#pragma unroll
  for (int e = 0; e < 8; ++e) acc[e] = 0.f;
#pragma unroll
  for (int i = 0; i < 4; ++i) {
    const int d = i * 256 + lane * 4;
    float4 xv = *(const float4*)(xr + d);
    ushort4 h;
    h.x = f2bf(xv.x); h.y = f2bf(xv.y); h.z = f2bf(xv.z); h.w = f2bf(xv.w);
    *(ushort4*)(xbf + (size_t)t * D_DIM + d) = h;
    const float xs[4] = {xv.x, xv.y, xv.z, xv.w};
#pragma unroll
    for (int j = 0; j < 4; ++j) {
      const float4* swp = (const float4*)(sw + (size_t)(d + j) * 8);
      float4 w0 = swp[0], w1 = swp[1];
      acc[0] += xs[j] * w0.x; acc[1] += xs[j] * w0.y;
      acc[2] += xs[j] * w0.z; acc[3] += xs[j] * w0.w;
      acc[4] += xs[j] * w1.x; acc[5] += xs[j] * w1.y;
      acc[6] += xs[j] * w1.z; acc[7] += xs[j] * w1.w;
    }
  }
#pragma unroll
  for (int e = 0; e < 8; ++e) {
    float v = acc[e];
    for (int o = 32; o > 0; o >>= 1) v += __shfl_down(v, o, 64);
    acc[e] = v;
  }
  if (lane == 0) {
#pragma unroll
    for (int e = 0; e < 8; ++e) acc[e] += sb[e];
    int am = 0; float mx = acc[0];
#pragma unroll
    for (int e = 1; e < 8; ++e) if (acc[e] > mx) { mx = acc[e]; am = e; }  // first-max wins
    float p[8]; float s = 0.f;
#pragma unroll
    for (int e = 0; e < 8; ++e) { p[e] = expf(acc[e] - mx); s += p[e]; }
    float inv = 1.0f / s;
    pmax_out[t] = inv;
    routes[t] = am;
#pragma unroll
    for (int e = 0; e < 8; ++e) probs[(size_t)t * 8 + e] = p[e] * inv;
  }
}

// ---------------- plan: counts/psums reduction + 128-aligned offsets ----------------
__global__ __launch_bounds__(256) void plan_kernel(
    const int* __restrict__ routes, const float* __restrict__ probs,
    int* __restrict__ off, float* __restrict__ out_counts,
    float* __restrict__ out_psums, float* __restrict__ out_zero) {
  __shared__ int cnt[8];
  __shared__ float red[256][8];
  const int tid = threadIdx.x;
  if (tid < 8) cnt[tid] = 0;
  __syncthreads();
  float loc[8];
#pragma unroll
  for (int e = 0; e < 8; ++e) loc[e] = 0.f;
  for (int t = tid; t < T_TOK; t += 256) {
    atomicAdd(&cnt[routes[t]], 1);
    const float4* p = (const float4*)(probs + (size_t)t * 8);
    float4 a = p[0], b = p[1];
    loc[0] += a.x; loc[1] += a.y; loc[2] += a.z; loc[3] += a.w;
    loc[4] += b.x; loc[5] += b.y; loc[6] += b.z; loc[7] += b.w;
  }
#pragma unroll
  for (int e = 0; e < 8; ++e) red[tid][e] = loc[e];
  __syncthreads();
  for (int s = 128; s >= 1; s >>= 1) {
    if (tid < s) {
#pragma unroll
      for (int e = 0; e < 8; ++e) red[tid][e] += red[tid + s][e];
    }
    __syncthreads();
  }
  if (tid == 0) {
    int o = 0;
    for (int e = 0; e < 8; ++e) { off[e] = o; o += ((cnt[e] + 127) >> 7) << 7; }
    off[8] = o;
    *out_zero = 0.0f;
  }
  if (tid < 8) {
    out_counts[tid] = (float)cnt[tid];
    out_psums[tid] = red[0][tid];
  }
}

// ---------------- scatter: token -> gathered slot ----------------
__global__ __launch_bounds__(256) void scatter_kernel(
    const int* __restrict__ routes, const int* __restrict__ off,
    int* __restrict__ cursor, int* __restrict__ perm_out,
    int* __restrict__ perm_src) {
  int t = blockIdx.x * 256 + threadIdx.x;
  if (t >= T_TOK) return;
  int e = routes[t];
  int pos = atomicAdd(&cursor[e], 1);
  perm_out[off[e] + pos] = t;
  perm_src[off[e] + pos] = t;
}

// ---------------- fused grouped GEMM, counted-vmcnt pipeline ----------------
// BMx{BN} tile, BK=64, 4 waves (2x2). A bf16 via global_load_lds (pre-swizzled src,
// key row&7). B: fp32 W -> float4 loads (depth-2 reg prefetch) -> cvt_pk bf16 ->
// 4x4 reg transpose -> ds_write_b64 swizzled with key (row>>2)&7 (write-conflict-free).
// Per K-step: A_STAGE(t+1) | B_LOAD(t+2) | MFMA | vmcnt(8+B_N) B_STORE(t+1) |
// vmcnt(B_N) lgkmcnt(0) s_barrier  -- B prefetch stays in flight across barriers.
template <int K_, int N_, int BN, bool FIRST, bool NCHUNK>
__global__ __launch_bounds__(256, 2) void gemm_fused(
    const unsigned short* __restrict__ A,    // FIRST: xbf [T][K_]; else H [RP][K_]
    const float* __restrict__ W,             // [E][K_][N_] fp32
    const float* __restrict__ Bias,          // [E][N_]
    const int* __restrict__ off,
    const int* __restrict__ perm_src, const int* __restrict__ perm_out,
    const float* __restrict__ pmax,
    unsigned short* __restrict__ Hout, float* __restrict__ Out) {
  constexpr int NT  = K_ / BK;      // even (16 or 64)
  constexpr int QPL = BN / 64;      // k-quads per lane in B staging (2 or 1)
  constexpr int NQ  = BN / 4;       // n-groups in B staging
  constexpr int B_N = QPL * 4;      // VMEM loads per B_LOAD (8 or 4)
  constexpr int FN  = BN / 32;      // B frags per wave (4 or 2)
  __shared__ __align__(16) unsigned short As[2][128 * 64];
  __shared__ __align__(16) unsigned short Bs[2][BN * 64];
  const int tid = threadIdx.x;
  // XCD-chunked bijective swizzle (grid size multiple of 8)
  const int nbx = gridDim.x, nby = gridDim.y;
  const int lin = blockIdx.y * nbx + blockIdx.x;
  const int chunkg = (nbx * nby) >> 3;
  const int newlin = (lin & 7) * chunkg + (lin >> 3);
  const int bx = NCHUNK ? (newlin / nby) : (newlin % nbx);
  const int by = NCHUNK ? (newlin % nby) : (newlin / nbx);
  const int rowbase = by * 128;
  if (rowbase >= off[8]) return;
  int e = 0;
#pragma unroll
  for (int i = 1; i <= 7; ++i) if (rowbase >= off[i]) e = i;
  const int n0 = bx * BN;
  const int wave = tid >> 6, lane = tid & 63;
  const int wm = wave >> 1, wn = wave & 1;
  const float* Wn0 = W + (size_t)e * K_ * N_ + n0;

  // A: per-lane pre-swizzled global sources; LDS linear, src chunk XOR'd (key row&7)
  const unsigned short* aSrc[4];
#pragma unroll
  for (int c = 0; c < 4; ++c) {
    int ca = (wave * 4 + c) * 64 + lane;      // 16B-chunk id, 0..1023
    int row = ca >> 3, slot = ca & 7;
    int sc = slot ^ (row & 7);
    size_t arow = FIRST ? (size_t)perm_src[rowbase + row] : (size_t)(rowbase + row);
    aSrc[c] = A + arow * K_ + sc * 8;
  }

  const int nq = lane & (NQ - 1);
  const int qgrp = lane / NQ;

  fx4 bregE[QPL][4], bregO[QPL][4];   // depth-2 B prefetch register sets

  auto A_STAGE = [&](int kt, unsigned short* Asb) {
#pragma unroll
    for (int c = 0; c < 4; ++c)
      load_lds16(aSrc[c] + kt, Asb + (wave * 4 + c) * 512);
  };
  auto B_LOAD = [&](int kt, fx4 (*br)[4]) {
#pragma unroll
    for (int q2 = 0; q2 < QPL; ++q2) {
      const int q = qgrp * QPL + q2;
#pragma unroll
      for (int j = 0; j < 4; ++j)
        br[q2][j] = *(const fx4*)(Wn0 + (size_t)(kt + wave * 16 + q * 4 + j) * N_ + nq * 4);
    }
  };
  auto B_STORE = [&](fx4 (*br)[4], unsigned short* Bsb) {
#pragma unroll
    for (int q2 = 0; q2 < QPL; ++q2) {
      const int q = qgrp * QPL + q2;
      const int c16 = wave * 2 + (q >> 1);
      const int h4 = (q & 1) * 4;            // 8B half (u16 units)
#pragma unroll
      for (int i = 0; i < 4; ++i) {
        const int nl = nq * 4 + i;
        uint32_t d0 = cvtpk_bf16(br[q2][0][i], br[q2][1][i]);
        uint32_t d1 = cvtpk_bf16(br[q2][2][i], br[q2][3][i]);
        *(uint2*)(Bsb + nl * 64 + (c16 ^ ((nl >> 2) & 7)) * 8 + h4) = make_uint2(d0, d1);
      }
    }
  };

  fx4 acc[4][FN];
#pragma unroll
  for (int a = 0; a < 4; ++a)
#pragma unroll
    for (int b = 0; b < FN; ++b) acc[a][b] = (fx4){0.f, 0.f, 0.f, 0.f};

  auto COMPUTE = [&](const unsigned short* Asb, const unsigned short* Bsb) {
    __builtin_amdgcn_s_setprio(1);
#pragma unroll
    for (int kk = 0; kk < 2; ++kk) {
      bfx8 af[4], bf[FN];
#pragma unroll
      for (int fm = 0; fm < 4; ++fm) {
        int r = wm * 64 + fm * 16 + (lane & 15);
        int c = (kk * 4 + (lane >> 4)) ^ (r & 7);
        af[fm] = *(const bfx8*)(Asb + r * 64 + c * 8);
      }
#pragma unroll
      for (int fn = 0; fn < FN; ++fn) {
        int nn = wn * (BN / 2) + fn * 16 + (lane & 15);
        int c = (kk * 4 + (lane >> 4)) ^ ((nn >> 2) & 7);
        bf[fn] = *(const bfx8*)(Bsb + nn * 64 + c * 8);
      }
#pragma unroll
      for (int fm = 0; fm < 4; ++fm)
#pragma unroll
        for (int fn = 0; fn < FN; ++fn)
          acc[fm][fn] = __builtin_amdgcn_mfma_f32_16x16x32_bf16(
              af[fm], bf[fn], acc[fm][fn], 0, 0, 0);
    }
    __builtin_amdgcn_s_setprio(0);
  };

  // ---- prologue: tile0 -> buf0 (B via setE), tile1 B -> setO ----
  B_LOAD(0, bregE);
  __builtin_amdgcn_sched_barrier(0);         // keep B0 before A0 in VMEM FIFO
  A_STAGE(0, As[0]);
  vm_wait<8>();                              // B0 done (A0 flying)
  B_STORE(bregE, Bs[0]);
  B_LOAD(BK, bregO);
  vm_wait_lgkm<B_N>();                       // A0 done (B1 flying)
  __builtin_amdgcn_s_barrier();

  // ---- main loop, pairs (even t: buf0/setE-load, odd t: buf1/setO-load) ----
  for (int t = 0; t < NT - 2; t += 2) {
    // iter t: compute buf0
    A_STAGE((t + 1) * BK, As[1]);
    __builtin_amdgcn_sched_barrier(0);       // A(t+1) before B(t+2) in FIFO
    B_LOAD((t + 2) * BK, bregE);
    COMPUTE(As[0], Bs[0]);
    vm_wait<8 + B_N>();                      // B(t+1) done; A(t+1),B(t+2) flying
    B_STORE(bregO, Bs[1]);
    vm_wait_lgkm<B_N>();                     // A(t+1) done; B(t+2) flying
    __builtin_amdgcn_s_barrier();
    // iter t+1: compute buf1
    A_STAGE((t + 2) * BK, As[0]);
    __builtin_amdgcn_sched_barrier(0);
    B_LOAD((t + 3) * BK, bregO);
    COMPUTE(As[1], Bs[1]);
    vm_wait<8 + B_N>();
    B_STORE(bregE, Bs[0]);
    vm_wait_lgkm<B_N>();
    __builtin_amdgcn_s_barrier();
  }
  // iter NT-2 (even): compute buf0; stage last A; store last B (setO)
  A_STAGE((NT - 1) * BK, As[1]);
  COMPUTE(As[0], Bs[0]);
  vm_wait<8>();                              // B(NT-1) done (A(NT-1) flying)
  B_STORE(bregO, Bs[1]);
  vm_wait_lgkm<0>();
  __builtin_amdgcn_s_barrier();
  // iter NT-1: compute buf1
  COMPUTE(As[1], Bs[1]);

  // ---- epilogue ----
  const int colbase = n0 + wn * (BN / 2);
  if (FIRST) {
#pragma unroll
    for (int fn = 0; fn < FN; ++fn) {
      int colg = colbase + fn * 16 + (lane & 15);
      float bv = Bias[(size_t)e * N_ + colg];
#pragma unroll
      for (int fm = 0; fm < 4; ++fm) {
        int rg = rowbase + wm * 64 + fm * 16 + ((lane >> 4) << 2);
#pragma unroll
        for (int j = 0; j < 4; ++j) {
          float v = fmaxf(acc[fm][fn][j] + bv, 0.f);
          Hout[(size_t)(rg + j) * N_ + colg] = f2bf(v);
        }
      }
    }
  } else {
#pragma unroll
    for (int fm = 0; fm < 4; ++fm) {
      int rg = rowbase + wm * 64 + fm * 16 + ((lane >> 4) << 2);
#pragma unroll
      for (int j = 0; j < 4; ++j) {
        int tok = perm_out[rg + j];
        if (tok < 0) continue;
        float pm = pmax[tok];
#pragma unroll
        for (int fn = 0; fn < FN; ++fn) {
          int colg = colbase + fn * 16 + (lane & 15);
          Out[(size_t)tok * N_ + colg] = (acc[fm][fn][j] + Bias[(size_t)e * N_ + colg]) * pm;
        }
      }
    }
  }
}

extern "C" void kernel_launch(void* const* d_in, const int* in_sizes, int n_in,
                              void* d_out, int out_size, void* d_ws, size_t ws_size,
                              hipStream_t stream) {
  const float* x  = (const float*)d_in[0];
  const float* sw = (const float*)d_in[1];
  const float* sb = (const float*)d_in[2];
  const float* w1 = (const float*)d_in[3];
  const float* b1 = (const float*)d_in[4];
  const float* w2 = (const float*)d_in[5];
  const float* b2 = (const float*)d_in[6];
  float* out = (float*)d_out;

  char* ws = (char*)d_ws;
  int*   off      = (int*)(ws + 0);          // 9 ints
  int*   cursor   = (int*)(ws + 512);        // 8 ints
  int*   routes   = (int*)(ws + 1024);       // 2048 ints
  int*   perm_out = (int*)(ws + 16384);      // RPMAX ints (pads -1)
  int*   perm_src = (int*)(ws + 32768);      // RPMAX ints (pads 0)
  float* probs    = (float*)(ws + 49152);    // 2048x8 fp32
  unsigned short* xbf = (unsigned short*)(ws + (1u << 20));   // 4 MB
  unsigned short* H   = (unsigned short*)(ws + (8u << 20));   // RPMAX x 4096 bf16 = 24 MB

  // d_out layout: final(2097152) | counts(8) | psums(8) | 0(1) | pmax(2048)
  float* out_final  = out;
  float* out_counts = out + 2097152;
  float* out_psums  = out + 2097160;
  float* out_zero   = out + 2097168;
  float* out_pmax   = out + 2097169;

  hipMemsetAsync(ws + 512, 0, 64, stream);              // cursor
  hipMemsetAsync(ws + 16384, 0xFF, RPMAX * 4, stream);  // perm_out = -1
  hipMemsetAsync(ws + 32768, 0x00, RPMAX * 4, stream);  // perm_src = 0

  router_kernel<<<T_TOK / 4, 256, 0, stream>>>(x, sw, sb, out_pmax, routes, probs, xbf);
  plan_kernel<<<1, 256, 0, stream>>>(routes, probs, off, out_counts, out_psums, out_zero);
  scatter_kernel<<<(T_TOK + 255) / 256, 256, 0, stream>>>(routes, off, cursor,
                                                          perm_out, perm_src);

  // GEMM1: gather(xbf)[RP,1024] x W1 -> H (relu, bf16). n-chunked XCD swizzle.
  gemm_fused<D_DIM, F_DIM, 128, true, true>
      <<<dim3(F_DIM / 128, RPMAX / 128), 256, 0, stream>>>(
          xbf, w1, b1, off, perm_src, perm_out, nullptr, H, nullptr);
  // GEMM2: H[RP,4096] x W2 -> out (bias, *pmax, scatter fp32). m-chunked swizzle.
  gemm_fused<F_DIM, D_DIM, 64, false, false>
      <<<dim3(D_DIM / 64, RPMAX / 128), 256, 0, stream>>>(
          H, w2, b2, off, perm_src, perm_out, out_pmax, nullptr, out_final);
}

// Round 6
// 161.269 us; speedup vs baseline: 3.9956x; 1.1505x over previous
//
#include <hip/hip_runtime.h>
#include <stdint.h>

// Problem constants (B=2,S=1024,D=1024,F=4096,E=8)
#define T_TOK 2048
#define D_DIM 1024
#define F_DIM 4096
#define E_NUM 8
#define RPMAX 3072   // max padded rows: sum of per-expert ceil(cnt,128)
#define BK 64

typedef __attribute__((ext_vector_type(8))) short bfx8;   // 8 bf16 (4 VGPR)
typedef __attribute__((ext_vector_type(4))) float fx4;    // MFMA accum / staging

__device__ __forceinline__ unsigned short f2bf(float f) {
  union { float f; uint32_t u; } v; v.f = f;
  uint32_t u = v.u;
  u += 0x7FFFu + ((u >> 16) & 1u);   // round-to-nearest-even
  return (unsigned short)(u >> 16);
}

__device__ __forceinline__ void load_lds16(const unsigned short* g, unsigned short* l) {
  __builtin_amdgcn_global_load_lds(
      (const __attribute__((address_space(1))) void*)g,
      (__attribute__((address_space(3))) void*)l, 16, 0, 0);
}

__device__ __forceinline__ uint32_t cvtpk_bf16(float lo, float hi) {
  uint32_t d;
  asm("v_cvt_pk_bf16_f32 %0, %1, %2" : "=v"(d) : "v"(lo), "v"(hi));
  return d;
}

template <int N>
__device__ __forceinline__ void vm_wait_lgkm() {
  if constexpr (N == 0) asm volatile("s_waitcnt vmcnt(0) lgkmcnt(0)" ::: "memory");
  else if constexpr (N == 8) asm volatile("s_waitcnt vmcnt(8) lgkmcnt(0)" ::: "memory");
  else if constexpr (N == 12) asm volatile("s_waitcnt vmcnt(12) lgkmcnt(0)" ::: "memory");
}

// ---------------- router: logits, softmax, argmax; NO global atomics ----------------
__global__ __launch_bounds__(256) void router_kernel(
    const float* __restrict__ x, const float* __restrict__ sw,
    const float* __restrict__ sb, float* __restrict__ pmax_out,
    int* __restrict__ routes, float* __restrict__ probs,
    unsigned short* __restrict__ xbf) {
  const int wave = threadIdx.x >> 6, lane = threadIdx.x & 63;
  const int t = blockIdx.x * 4 + wave;
  const float* xr = x + (size_t)t * D_DIM;
  float acc[8];
#pragma unroll
  for (int e = 0; e < 8; ++e) acc[e] = 0.f;
#pragma unroll
  for (int i = 0; i < 4; ++i) {
    const int d = i * 256 + lane * 4;
    float4 xv = *(const float4*)(xr + d);
    ushort4 h;
    h.x = f2bf(xv.x); h.y = f2bf(xv.y); h.z = f2bf(xv.z); h.w = f2bf(xv.w);
    *(ushort4*)(xbf + (size_t)t * D_DIM + d) = h;
    const float xs[4] = {xv.x, xv.y, xv.z, xv.w};
#pragma unroll
    for (int j = 0; j < 4; ++j) {
      const float4* swp = (const float4*)(sw + (size_t)(d + j) * 8);
      float4 w0 = swp[0], w1 = swp[1];
      acc[0] += xs[j] * w0.x; acc[1] += xs[j] * w0.y;
      acc[2] += xs[j] * w0.z; acc[3] += xs[j] * w0.w;
      acc[4] += xs[j] * w1.x; acc[5] += xs[j] * w1.y;
      acc[6] += xs[j] * w1.z; acc[7] += xs[j] * w1.w;
    }
  }
#pragma unroll
  for (int e = 0; e < 8; ++e) {
    float v = acc[e];
    for (int o = 32; o > 0; o >>= 1) v += __shfl_down(v, o, 64);
    acc[e] = v;
  }
  if (lane == 0) {
#pragma unroll
    for (int e = 0; e < 8; ++e) acc[e] += sb[e];
    int am = 0; float mx = acc[0];
#pragma unroll
    for (int e = 1; e < 8; ++e) if (acc[e] > mx) { mx = acc[e]; am = e; }  // first-max wins
    float p[8]; float s = 0.f;
#pragma unroll
    for (int e = 0; e < 8; ++e) { p[e] = expf(acc[e] - mx); s += p[e]; }
    float inv = 1.0f / s;
    pmax_out[t] = inv;
    routes[t] = am;
#pragma unroll
    for (int e = 0; e < 8; ++e) probs[(size_t)t * 8 + e] = p[e] * inv;
  }
}

// ---------------- plan: counts/psums reduce, offsets, cursor zero, perm init ----------
__global__ __launch_bounds__(256) void plan_kernel(
    const int* __restrict__ routes, const float* __restrict__ probs,
    int* __restrict__ off, int* __restrict__ cursor,
    int* __restrict__ perm_out, int* __restrict__ perm_src,
    float* __restrict__ out_counts, float* __restrict__ out_psums,
    float* __restrict__ out_zero) {
  __shared__ int cnt[8];
  __shared__ float red[256][8];
  const int tid = threadIdx.x;
  if (tid < 8) { cnt[tid] = 0; cursor[tid] = 0; }
  for (int i = tid; i < RPMAX; i += 256) { perm_out[i] = -1; perm_src[i] = 0; }
  __syncthreads();
  float loc[8];
#pragma unroll
  for (int e = 0; e < 8; ++e) loc[e] = 0.f;
  for (int t = tid; t < T_TOK; t += 256) {
    atomicAdd(&cnt[routes[t]], 1);
    const float4* p = (const float4*)(probs + (size_t)t * 8);
    float4 a = p[0], b = p[1];
    loc[0] += a.x; loc[1] += a.y; loc[2] += a.z; loc[3] += a.w;
    loc[4] += b.x; loc[5] += b.y; loc[6] += b.z; loc[7] += b.w;
  }
#pragma unroll
  for (int e = 0; e < 8; ++e) red[tid][e] = loc[e];
  __syncthreads();
  for (int s = 128; s >= 1; s >>= 1) {
    if (tid < s) {
#pragma unroll
      for (int e = 0; e < 8; ++e) red[tid][e] += red[tid + s][e];
    }
    __syncthreads();
  }
  if (tid == 0) {
    int o = 0;
    for (int e = 0; e < 8; ++e) { off[e] = o; o += ((cnt[e] + 127) >> 7) << 7; }
    off[8] = o;
    *out_zero = 0.0f;
  }
  if (tid < 8) {
    out_counts[tid] = (float)cnt[tid];
    out_psums[tid] = red[0][tid];
  }
}

// ---------------- scatter: token -> gathered slot ----------------
__global__ __launch_bounds__(256) void scatter_kernel(
    const int* __restrict__ routes, const int* __restrict__ off,
    int* __restrict__ cursor, int* __restrict__ perm_out,
    int* __restrict__ perm_src) {
  int t = blockIdx.x * 256 + threadIdx.x;
  if (t >= T_TOK) return;
  int e = routes[t];
  int pos = atomicAdd(&cursor[e], 1);
  perm_out[off[e] + pos] = t;
  perm_src[off[e] + pos] = t;
}

// ---------------- fused grouped GEMM, deep pipeline ----------------
// 128x64 tile, BK=64, 4 waves (2m x 2n). A bf16 via global_load_lds, staged TWO
// K-steps ahead into 3 rotating LDS buffers (pre-swizzled src, key row&7).
// B: fp32 W -> float4 (depth-2 reg prefetch) -> cvt_pk bf16 -> 4x4 reg transpose ->
// ds_write_b64, swizzle key ((nl>>2)+2*(nl&3))&7. One barrier/K-step; vmcnt never
// drained below the 8 in-flight prefetch loads in the main loop.
template <int K_, int N_, bool FIRST, bool NCHUNK>
__global__ __launch_bounds__(256, 2) void gemm_fused(
    const unsigned short* __restrict__ A,    // FIRST: xbf [T][K_]; else H [RP][K_]
    const float* __restrict__ W,             // [E][K_][N_] fp32
    const float* __restrict__ Bias,          // [E][N_]
    const int* __restrict__ off,
    const int* __restrict__ perm_src, const int* __restrict__ perm_out,
    const float* __restrict__ pmax,
    unsigned short* __restrict__ Hout, float* __restrict__ Out) {
  constexpr int NT = K_ / BK;                // 16 or 64 (even, >=4)
  __shared__ __align__(16) unsigned short As[3][128 * 64];
  __shared__ __align__(16) unsigned short Bs[2][64 * 64];
  const int tid = threadIdx.x;
  // XCD-chunked bijective swizzle (grid size multiple of 8)
  const int nbx = gridDim.x, nby = gridDim.y;
  const int lin = blockIdx.y * nbx + blockIdx.x;
  const int chunkg = (nbx * nby) >> 3;
  const int newlin = (lin & 7) * chunkg + (lin >> 3);
  const int bx = NCHUNK ? (newlin / nby) : (newlin % nbx);
  const int by = NCHUNK ? (newlin % nby) : (newlin / nbx);
  const int rowbase = by * 128;
  if (rowbase >= off[8]) return;
  int e = 0;
#pragma unroll
  for (int i = 1; i <= 7; ++i) if (rowbase >= off[i]) e = i;
  const int n0 = bx * 64;
  const int wave = tid >> 6, lane = tid & 63;
  const int wm = wave >> 1, wn = wave & 1;
  const float* Wn0 = W + (size_t)e * K_ * N_ + n0;

  // A: per-lane pre-swizzled global sources; LDS linear, src chunk XOR'd (key row&7)
  const unsigned short* aSrc[4];
#pragma unroll
  for (int c = 0; c < 4; ++c) {
    int ca = (wave * 4 + c) * 64 + lane;      // 16B-chunk id, 0..1023
    int row = ca >> 3, slot = ca & 7;
    int sc = slot ^ (row & 7);
    size_t arow = FIRST ? (size_t)perm_src[rowbase + row] : (size_t)(rowbase + row);
    aSrc[c] = A + arow * K_ + sc * 8;
  }

  const int nq = lane & 15;                  // n-quad 0..15
  const int qg = lane >> 4;                  // k-quad group 0..3
  fx4 bregE[4], bregO[4];                    // depth-2 B prefetch register sets

  auto A_STAGE = [&](int kt, unsigned short* Asb) {
#pragma unroll
    for (int c = 0; c < 4; ++c)
      load_lds16(aSrc[c] + kt, Asb + (wave * 4 + c) * 512);
  };
  auto B_LOAD = [&](int kt, fx4* br) {
#pragma unroll
    for (int j = 0; j < 4; ++j)
      br[j] = *(const fx4*)(Wn0 + (size_t)(kt + wave * 16 + qg * 4 + j) * N_ + nq * 4);
  };
  auto B_STORE = [&](fx4* br, unsigned short* Bsb) {
    const int c16 = wave * 2 + (qg >> 1);
    const int h4 = (qg & 1) * 4;             // 8B half (u16 units)
#pragma unroll
    for (int i = 0; i < 4; ++i) {
      const int nl = nq * 4 + i;
      const int key = ((nl >> 2) + 2 * (nl & 3)) & 7;
      uint32_t d0 = cvtpk_bf16(br[0][i], br[1][i]);
      uint32_t d1 = cvtpk_bf16(br[2][i], br[3][i]);
      *(uint2*)(Bsb + nl * 64 + (c16 ^ key) * 8 + h4) = make_uint2(d0, d1);
    }
  };

  fx4 acc[4][2];
#pragma unroll
  for (int a = 0; a < 4; ++a)
#pragma unroll
    for (int b = 0; b < 2; ++b) acc[a][b] = (fx4){0.f, 0.f, 0.f, 0.f};

  auto COMPUTE = [&](const unsigned short* Asb, const unsigned short* Bsb) {
    __builtin_amdgcn_s_setprio(1);
#pragma unroll
    for (int kk = 0; kk < 2; ++kk) {
      bfx8 af[4], bf[2];
#pragma unroll
      for (int fm = 0; fm < 4; ++fm) {
        int r = wm * 64 + fm * 16 + (lane & 15);
        int c = (kk * 4 + (lane >> 4)) ^ (r & 7);
        af[fm] = *(const bfx8*)(Asb + r * 64 + c * 8);
      }
#pragma unroll
      for (int fn = 0; fn < 2; ++fn) {
        int nn = wn * 32 + fn * 16 + (lane & 15);
        int key = ((nn >> 2) + 2 * (nn & 3)) & 7;
        int c = (kk * 4 + (lane >> 4)) ^ key;
        bf[fn] = *(const bfx8*)(Bsb + nn * 64 + c * 8);
      }
#pragma unroll
      for (int fm = 0; fm < 4; ++fm)
#pragma unroll
        for (int fn = 0; fn < 2; ++fn)
          acc[fm][fn] = __builtin_amdgcn_mfma_f32_16x16x32_bf16(
              af[fm], bf[fn], acc[fm][fn], 0, 0, 0);
    }
    __builtin_amdgcn_s_setprio(0);
  };

  unsigned short *a0 = As[0], *a1 = As[1], *a2 = As[2];

  // ---- prologue: A0,B0,A1,B1 issued in FIFO order; store B0; barrier ----
  A_STAGE(0, a0);
  __builtin_amdgcn_sched_barrier(0);
  B_LOAD(0, bregE);
  __builtin_amdgcn_sched_barrier(0);
  A_STAGE(BK, a1);
  __builtin_amdgcn_sched_barrier(0);
  B_LOAD(BK, bregO);
  B_STORE(bregE, Bs[0]);                     // implicit reg-wait drains A0,B0
  vm_wait_lgkm<8>();                         // A1+B1 stay in flight
  __builtin_amdgcn_s_barrier();

  // ---- main loop: pairs; compute t from a0/Bs[t&1]; stage A(t+2)->a2, B(t+2) ----
  for (int t = 0; t < NT - 2; t += 2) {
    // even iter t
    A_STAGE((t + 2) * BK, a2);
    __builtin_amdgcn_sched_barrier(0);
    B_LOAD((t + 2) * BK, bregE);
    COMPUTE(a0, Bs[0]);
    B_STORE(bregO, Bs[1]);                   // waits B(t+1) -> drains A(t+1)
    vm_wait_lgkm<8>();                       // A(t+2)+B(t+2) remain in flight
    __builtin_amdgcn_s_barrier();
    { unsigned short* tmp = a0; a0 = a1; a1 = a2; a2 = tmp; }
    // odd iter t+1
    if (t + 3 < NT) {
      A_STAGE((t + 3) * BK, a2);
      __builtin_amdgcn_sched_barrier(0);
      B_LOAD((t + 3) * BK, bregO);
    }
    COMPUTE(a0, Bs[1]);
    B_STORE(bregE, Bs[0]);                   // waits B(t+2) -> drains A(t+2)
    vm_wait_lgkm<8>();
    __builtin_amdgcn_s_barrier();
    { unsigned short* tmp = a0; a0 = a1; a1 = a2; a2 = tmp; }
  }
  // tail: iter NT-2 (even), nothing new to issue
  COMPUTE(a0, Bs[0]);
  B_STORE(bregO, Bs[1]);                     // B(NT-1); drains A(NT-1)
  vm_wait_lgkm<0>();
  __builtin_amdgcn_s_barrier();
  { unsigned short* tmp = a0; a0 = a1; a1 = a2; a2 = tmp; }
  COMPUTE(a0, Bs[1]);                        // iter NT-1

  // ---- epilogue ----
  const int colbase = n0 + wn * 32;
  if (FIRST) {
#pragma unroll
    for (int fn = 0; fn < 2; ++fn) {
      int colg = colbase + fn * 16 + (lane & 15);
      float bv = Bias[(size_t)e * N_ + colg];
#pragma unroll
      for (int fm = 0; fm < 4; ++fm) {
        int rg = rowbase + wm * 64 + fm * 16 + ((lane >> 4) << 2);
#pragma unroll
        for (int j = 0; j < 4; ++j) {
          float v = fmaxf(acc[fm][fn][j] + bv, 0.f);
          Hout[(size_t)(rg + j) * N_ + colg] = f2bf(v);
        }
      }
    }
  } else {
#pragma unroll
    for (int fm = 0; fm < 4; ++fm) {
      int rg = rowbase + wm * 64 + fm * 16 + ((lane >> 4) << 2);
#pragma unroll
      for (int j = 0; j < 4; ++j) {
        int tok = perm_out[rg + j];
        if (tok < 0) continue;
        float pm = pmax[tok];
#pragma unroll
        for (int fn = 0; fn < 2; ++fn) {
          int colg = colbase + fn * 16 + (lane & 15);
          Out[(size_t)tok * N_ + colg] = (acc[fm][fn][j] + Bias[(size_t)e * N_ + colg]) * pm;
        }
      }
    }
  }
}

extern "C" void kernel_launch(void* const* d_in, const int* in_sizes, int n_in,
                              void* d_out, int out_size, void* d_ws, size_t ws_size,
                              hipStream_t stream) {
  const float* x  = (const float*)d_in[0];
  const float* sw = (const float*)d_in[1];
  const float* sb = (const float*)d_in[2];
  const float* w1 = (const float*)d_in[3];
  const float* b1 = (const float*)d_in[4];
  const float* w2 = (const float*)d_in[5];
  const float* b2 = (const float*)d_in[6];
  float* out = (float*)d_out;

  char* ws = (char*)d_ws;
  int*   off      = (int*)(ws + 0);          // 9 ints
  int*   cursor   = (int*)(ws + 512);        // 8 ints
  int*   routes   = (int*)(ws + 1024);       // 2048 ints
  int*   perm_out = (int*)(ws + 16384);      // RPMAX ints (pads -1)
  int*   perm_src = (int*)(ws + 32768);      // RPMAX ints (pads 0)
  float* probs    = (float*)(ws + 49152);    // 2048x8 fp32
  unsigned short* xbf = (unsigned short*)(ws + (1u << 20));   // 4 MB
  unsigned short* H   = (unsigned short*)(ws + (8u << 20));   // RPMAX x 4096 bf16 = 24 MB

  // d_out layout: final(2097152) | counts(8) | psums(8) | 0(1) | pmax(2048)
  float* out_final  = out;
  float* out_counts = out + 2097152;
  float* out_psums  = out + 2097160;
  float* out_zero   = out + 2097168;
  float* out_pmax   = out + 2097169;

  router_kernel<<<T_TOK / 4, 256, 0, stream>>>(x, sw, sb, out_pmax, routes, probs, xbf);
  plan_kernel<<<1, 256, 0, stream>>>(routes, probs, off, cursor, perm_out, perm_src,
                                     out_counts, out_psums, out_zero);
  scatter_kernel<<<(T_TOK + 255) / 256, 256, 0, stream>>>(routes, off, cursor,
                                                          perm_out, perm_src);

  // GEMM1: gather(xbf)[RP,1024] x W1 -> H (relu, bf16). n-chunked XCD swizzle.
  gemm_fused<D_DIM, F_DIM, true, true>
      <<<dim3(F_DIM / 64, RPMAX / 128), 256, 0, stream>>>(
          xbf, w1, b1, off, perm_src, perm_out, nullptr, H, nullptr);
  // GEMM2: H[RP,4096] x W2 -> out (bias, *pmax, scatter fp32). m-chunked swizzle.
  gemm_fused<F_DIM, D_DIM, false, false>
      <<<dim3(D_DIM / 64, RPMAX / 128), 256, 0, stream>>>(
          H, w2, b2, off, perm_src, perm_out, out_pmax, nullptr, out_final);
}